// Round 2
// baseline (832.210 us; speedup 1.0000x reference)
//
#include <hip/hip_runtime.h>

typedef short short8 __attribute__((ext_vector_type(8)));
typedef float f32x4 __attribute__((ext_vector_type(4)));

#define DEVINL __device__ __forceinline__

// ---------------- host: sedenion sign/index table (Cayley-Dickson) ----------
struct SedTab { signed char s[256]; unsigned char j[256]; };

static void cd_mult_host(const float* a, const float* b, float* r, int n) {
    if (n == 1) { r[0] = a[0] * b[0]; return; }
    int h = n / 2;
    float cb1[8], cb2[8], t1[8], t2[8], t3[8], t4[8];
    cb1[0] = b[0]; for (int i = 1; i < h; ++i) cb1[i] = -b[i];        // conj(b1)
    cb2[0] = b[h]; for (int i = 1; i < h; ++i) cb2[i] = -b[h + i];    // conj(b2)
    cd_mult_host(a,     b,   t1, h);   // a1*b1
    cd_mult_host(cb2,   a+h, t2, h);   // conj(b2)*a2
    cd_mult_host(b+h,   a,   t3, h);   // b2*a1
    cd_mult_host(a+h,   cb1, t4, h);   // a2*conj(b1)
    for (int i = 0; i < h; ++i) { r[i] = t1[i] - t2[i]; r[h + i] = t3[i] + t4[i]; }
}

static SedTab build_sed() {
    SedTab t{};
    for (int i = 0; i < 16; ++i)
        for (int jj = 0; jj < 16; ++jj) {
            float a[16] = {0}, b[16] = {0}, r[16] = {0};
            a[i] = 1.0f; b[jj] = 1.0f;
            cd_mult_host(a, b, r, 16);
            for (int k = 0; k < 16; ++k)
                if (r[k] != 0.0f) {
                    t.s[i * 16 + k] = (r[k] > 0.f) ? 1 : -1;
                    t.j[i * 16 + k] = (unsigned char)jj;
                }
        }
    return t;
}
static const SedTab g_sed = build_sed();

// ---------------- device helpers -------------------------------------------
DEVINL unsigned short f2bf(float v) {
    union { float f; unsigned int u; } c; c.f = v;
    unsigned int r = (c.u + 0x7FFFu + ((c.u >> 16) & 1u)) >> 16;
    return (unsigned short)r;
}
DEVINL float bf2f(unsigned short u) {
    union { unsigned int i; float f; } c; c.i = ((unsigned int)u) << 16; return c.f;
}

DEVINL float gelu_f(float v) {   // tanh-approx == v*sigmoid(1.5958(v+0.044715v^3)), |err|<1.1e-3
    float u = 1.5957691216f * (v + 0.044715f * v * v * v);
    // v_rcp_f32 instead of IEEE divide sequence (~8 fewer VALU/elem; ~1ulp)
    return v * __builtin_amdgcn_rcpf(1.0f + __expf(-u));
}

DEVINL void gl2lds16(const void* g, void* l) {
    __builtin_amdgcn_global_load_lds((__attribute__((address_space(1))) const unsigned int*)g,
                                     (__attribute__((address_space(3))) unsigned int*)l, 16, 0, 0);
}

// xor-swizzle position of element k within a row (groups of 64, chunks of 8)
DEVINL int swz(int k, int row) {
    return (k & ~63) | ((((k >> 3) ^ row) & 7) << 3) | (k & 7);
}

// ---------------- wfT builder: wfT[n=(k,e)][kk=(i,dd)] = s(i,k)*w_sed[j,dd,e]
__global__ __launch_bounds__(256) void build_wft(const float* __restrict__ w_sed,
                                                 unsigned short* __restrict__ wfT,
                                                 SedTab tab) {
    __shared__ float t[32][33];
    int n0 = blockIdx.y * 32, kk0 = blockIdx.x * 32;
    int k = n0 / 192, i = kk0 / 192;            // tiles never straddle (192 = 6*32)
    int j = tab.j[i * 16 + k];
    float s = (float)tab.s[i * 16 + k];
    int e0 = n0 - k * 192, dd0 = kk0 - i * 192;
    int tx = threadIdx.x & 31, ty = threadIdx.x >> 5;
    const float* base = w_sed + ((size_t)j * 192 + dd0) * 192 + e0;
    for (int it = 0; it < 4; ++it) {
        int row = ty + it * 8;                  // row = dd index, tx = e index
        t[row][tx] = base[(size_t)row * 192 + tx];
    }
    __syncthreads();
    unsigned short* ob = wfT + (size_t)n0 * 3072 + kk0;
    for (int it = 0; it < 4; ++it) {
        int row = ty + it * 8;                  // out row = e index, tx = dd index
        ob[(size_t)row * 3072 + tx] = f2bf(s * t[tx][row]);
    }
}

// ---------------- small weights → [N][K] bf16 (fc1/fc2 pre-swizzled) --------
__global__ __launch_bounds__(256) void prep_w(const float* __restrict__ proj,
                                              const float* __restrict__ fc1,
                                              const float* __restrict__ fc2,
                                              unsigned short* __restrict__ projT,
                                              unsigned short* __restrict__ fc1T,
                                              unsigned short* __restrict__ fc2T) {
    int t = blockIdx.x * 256 + threadIdx.x;     // grid covers 147456
    if (t < 192 * 192) projT[t] = f2bf(proj[(t % 192) * 192 + t / 192]);
    if (t < 768 * 192) {
        int n = t / 192, k = t % 192;
        fc1T[n * 192 + swz(k, n)] = f2bf(fc1[(size_t)k * 768 + n]);
    }
    if (t < 192 * 768) {
        int o = t / 768, k = t % 768;
        fc2T[o * 768 + swz(k, o)] = f2bf(fc2[(size_t)k * 192 + o]);
    }
}

// ---------------- LN1 over channels + windowize; also emit raw x (bf16) -----
__global__ __launch_bounds__(256) void ln1_win(const float* __restrict__ x,
                                               const float* __restrict__ g,
                                               const float* __restrict__ bta,
                                               unsigned short* __restrict__ xw,
                                               unsigned short* __restrict__ xwin) {
    __shared__ float vals[192 * 65];
    __shared__ float ps[8][64];
    __shared__ float mrs[2][64];
    int t = threadIdx.x;
    int bid = blockIdx.x;
    int x0 = (bid & 3) << 6;
    int y  = (bid >> 2) & 255;
    int b  = bid >> 10;
    int px = t & 63, cg = t >> 6;
    const float* xp = x + ((size_t)b * 192 * 65536) + (size_t)y * 256 + x0 + px;
    float s = 0.f, s2 = 0.f;
    for (int c = cg; c < 192; c += 4) {
        float v = xp[(size_t)c * 65536];
        vals[c * 65 + px] = v;
        s += v; s2 += v * v;
    }
    ps[cg][px] = s; ps[cg + 4][px] = s2;
    __syncthreads();
    if (t < 64) {
        float S  = ps[0][t] + ps[1][t] + ps[2][t] + ps[3][t];
        float S2 = ps[4][t] + ps[5][t] + ps[6][t] + ps[7][t];
        float mean = S * (1.0f / 192.0f);
        float var  = S2 * (1.0f / 192.0f) - mean * mean;
        mrs[0][t] = mean;
        mrs[1][t] = rsqrtf(var + 1e-5f);
    }
    __syncthreads();
    int wh = y >> 2, wr = y & 3;
    for (int i = t; i < 192 * 64; i += 256) {
        int p = i / 192;
        int c = i - p * 192;
        float v = vals[c * 65 + p];
        int xx = x0 + p;
        int ww = xx >> 2, wc = xx & 3;
        int gp = ((b * 64 + wh) * 64 + ww) * 16 + wr * 4 + wc;
        size_t o = (size_t)gp * 192 + c;
        xwin[o] = f2bf(v);
        xw[o] = f2bf((v - mrs[0][p]) * mrs[1][p] * g[c] + bta[c]);
    }
}

// ---------------- bf16 MFMA GEMM, TM x TN, BK=64, XOR-swizzled LDS ----------
// A:[M,K] row-major bf16, BT:[N,K] row-major bf16 (pre-transposed B).
// EPI 0: outB bf16 = gelu(acc [+bias])                        (gemm1 sedenion)
// EPI 3: xres(bf16) += acc+bias; outB = LN2(xres) bf16, col-swizzled (gemm2)
template<int TM, int TN, int EPI>
__global__ __launch_bounds__(256, 2) void gemm_bf16(
        const unsigned short* __restrict__ A, const unsigned short* __restrict__ BT,
        const float* __restrict__ bias, unsigned short* __restrict__ outB,
        unsigned short* __restrict__ xresb,
        const float* __restrict__ g2, const float* __restrict__ b2,
        int K, int N) {
    constexpr int WN = TN / 2;
    constexpr int NT = WN / 16;
    constexpr int MT = TM / 32;
    constexpr int HR = TM / 2;
    __shared__ __align__(16) char smem[(TM * 64 + TN * 64) * 2];
    short* lsA = (short*)smem;
    short* lsB = (short*)(smem + TM * 64 * 2);
    int tid = threadIdx.x, lane = tid & 63, wid = tid >> 6;
    int wrow = wid >> 1, wcol = wid & 1;
    int lm = lane & 15, lq = lane >> 4;
    int bm = blockIdx.x * TM, bn = blockIdx.y * TN;
    const unsigned short* Ag = A + (size_t)bm * K;
    const unsigned short* Bg = BT + (size_t)bn * K;
    f32x4 acc[MT][NT] = {};
    for (int k0 = 0; k0 < K; k0 += 64) {
        #pragma unroll
        for (int it = 0; it < TM / 32; ++it) {      // stage A tile
            int p = (it * 4 + wid) * 64 + lane;
            int r = p >> 3;
            int q = (p & 7) ^ (r & 7);
            gl2lds16(Ag + (size_t)r * K + k0 + q * 8, lsA + (it * 4 + wid) * 512);
        }
        #pragma unroll
        for (int it = 0; it < TN / 32; ++it) {      // stage BT tile
            int p = (it * 4 + wid) * 64 + lane;
            int r = p >> 3;
            int q = (p & 7) ^ (r & 7);
            gl2lds16(Bg + (size_t)r * K + k0 + q * 8, lsB + (it * 4 + wid) * 512);
        }
        __syncthreads();
        #pragma unroll
        for (int s = 0; s < 2; ++s) {
            short8 af[MT], bfr[NT];
            #pragma unroll
            for (int mt = 0; mt < MT; ++mt) {
                int r = wrow * HR + mt * 16 + lm;
                int q = s * 4 + lq;
                int pos = r * 8 + (q ^ (r & 7));
                af[mt] = *(const short8*)&lsA[pos * 8];
            }
            #pragma unroll
            for (int nt = 0; nt < NT; ++nt) {
                int r = wcol * WN + nt * 16 + lm;
                int q = s * 4 + lq;
                int pos = r * 8 + (q ^ (r & 7));
                bfr[nt] = *(const short8*)&lsB[pos * 8];
            }
            #pragma unroll
            for (int mt = 0; mt < MT; ++mt)
                #pragma unroll
                for (int nt = 0; nt < NT; ++nt)
                    acc[mt][nt] = __builtin_amdgcn_mfma_f32_16x16x32_bf16(af[mt], bfr[nt], acc[mt][nt], 0, 0, 0);
        }
        __syncthreads();
    }
    // epilogue: C/D layout col=lane&15, row=lq*4+reg
    int rowB = bm + wrow * HR + lq * 4;
    int colB = bn + wcol * WN + lm;

    if constexpr (EPI == 0) {
        #pragma unroll
        for (int mt = 0; mt < MT; ++mt)
            #pragma unroll
            for (int nt = 0; nt < NT; ++nt)
                #pragma unroll
                for (int r = 0; r < 4; ++r) {
                    int gr = rowB + mt * 16 + r;
                    int gc = colB + nt * 16;
                    float v = acc[mt][nt][r];
                    if (bias) v += bias[gc];
                    outB[(size_t)gr * N + gc] = f2bf(gelu_f(v));
                }
    } else {
        // proj + residual into xres (bf16, in-place over xwin), fused LN2 →
        // outB (A3, col-swizzled for ffn_fused). TM=128, TN=192, bn=0.
        float sA[MT][4], s2A[MT][4];
        #pragma unroll
        for (int mt = 0; mt < MT; ++mt)
            #pragma unroll
            for (int r = 0; r < 4; ++r) { sA[mt][r] = 0.f; s2A[mt][r] = 0.f; }
        #pragma unroll
        for (int mt = 0; mt < MT; ++mt)
            #pragma unroll
            for (int nt = 0; nt < NT; ++nt)
                #pragma unroll
                for (int r = 0; r < 4; ++r) {
                    int gr = rowB + mt * 16 + r;
                    int gc = colB + nt * 16;
                    size_t o = (size_t)gr * 192 + gc;
                    float v = bf2f(xresb[o]) + acc[mt][nt][r] + bias[gc];
                    xresb[o] = f2bf(v);
                    acc[mt][nt][r] = v;
                    sA[mt][r] += v; s2A[mt][r] += v * v;
                }
        #pragma unroll
        for (int mt = 0; mt < MT; ++mt)
            #pragma unroll
            for (int r = 0; r < 4; ++r)
                #pragma unroll
                for (int msk = 1; msk < 16; msk <<= 1) {
                    sA[mt][r]  += __shfl_xor(sA[mt][r],  msk, 64);
                    s2A[mt][r] += __shfl_xor(s2A[mt][r], msk, 64);
                }
        float* psS   = (float*)smem;             // [128][2]
        float* psS2  = psS + 256;                // [128][2]
        float* pmean = psS2 + 256;               // [128]
        float* prsig = pmean + 128;              // [128]
        if (lm == 0) {
            #pragma unroll
            for (int mt = 0; mt < MT; ++mt)
                #pragma unroll
                for (int r = 0; r < 4; ++r) {
                    int rl = wrow * HR + mt * 16 + lq * 4 + r;
                    psS [rl * 2 + wcol] = sA[mt][r];
                    psS2[rl * 2 + wcol] = s2A[mt][r];
                }
        }
        __syncthreads();
        if (tid < TM) {
            float S  = psS[tid * 2]  + psS[tid * 2 + 1];
            float S2 = psS2[tid * 2] + psS2[tid * 2 + 1];
            float mean = S * (1.0f / 192.0f);
            float var  = S2 * (1.0f / 192.0f) - mean * mean;
            pmean[tid] = mean;
            prsig[tid] = rsqrtf(var + 1e-5f);
        }
        __syncthreads();
        float gw[NT], bw[NT];
        #pragma unroll
        for (int nt = 0; nt < NT; ++nt) {
            int gc = colB + nt * 16;
            gw[nt] = g2[gc]; bw[nt] = b2[gc];
        }
        #pragma unroll
        for (int mt = 0; mt < MT; ++mt)
            #pragma unroll
            for (int nt = 0; nt < NT; ++nt)
                #pragma unroll
                for (int r = 0; r < 4; ++r) {
                    int gr = rowB + mt * 16 + r;
                    int rl = wrow * HR + mt * 16 + lq * 4 + r;
                    int gc = colB + nt * 16;
                    float v = (acc[mt][nt][r] - pmean[rl]) * prsig[rl] * gw[nt] + bw[nt];
                    outB[(size_t)gr * 192 + swz(gc, gr)] = f2bf(v);
                }
    }
}

// ---------------- fused FFN: out = scatter(xres + gelu(A3@fc1+b1)@fc2 + b2) -
// A3: [131072][192] bf16 col-swizzled; fc1T [768][192], fc2T [192][768]
// pre-swizzled; xres bf16 plain.
// v3: 1024-thread blocks, 256 rows/block → LDS 104 KB, 16 waves/CU (was 8;
// v2 was issue-bound at 20% occupancy). A3 fragments in regs (as v2); fc1
// double-buffered, fc2 staged one phase ahead; counted-drain barrier scheme
// unchanged. Epilogue: acc2[..][0..3] already holds 4 consecutive rows =
// 4 window-cols → direct per-lane f32x4 BCHW store, LDS transpose deleted.
__global__ __launch_bounds__(1024, 4) void ffn_fused(
        const unsigned short* __restrict__ A3, const unsigned short* __restrict__ fc1T,
        const unsigned short* __restrict__ fc2T, const float* __restrict__ b1,
        const float* __restrict__ b2, const unsigned short* __restrict__ xresb,
        float* __restrict__ outF) {
    __shared__ __align__(16) char smem[106496];
    short* wA0 = (short*)smem;                    // [64][192]  fc1 slice buf 0
    short* wA1 = (short*)(smem + 24576);          // [64][192]  fc1 slice buf 1
    short* wB  = (short*)(smem + 49152);          // [192][64]  fc2 slice
    short* Sb  = (short*)(smem + 73728);          // [256][64]  gelu tile (wave-private rows)
    int tid = threadIdx.x, lane = tid & 63, wid = tid >> 6;   // wid 0..15
    int wrow = wid >> 1, wcol = wid & 1;                      // wrow 0..7
    int lm = lane & 15, lq = lane >> 4;
    int bm = blockIdx.x * 256;

    const unsigned short* A3g = A3 + (size_t)bm * 192;

    auto stage_fc1 = [&](int slice, short* dst) {             // 1536 16B-chunks
        const unsigned short* f1g = fc1T + (size_t)slice * 64 * 192;  // contiguous
        gl2lds16(f1g + (size_t)tid * 8, dst + tid * 8);
        if (tid < 512)
            gl2lds16(f1g + (size_t)(1024 + tid) * 8, dst + (1024 + tid) * 8);
    };
    auto stage_fc2 = [&](int slice) {                         // 1536 16B-chunks
        int kb = slice * 64;
        int ch = tid;                                         // 8 chunks/row
        gl2lds16(fc2T + (size_t)(ch >> 3) * 768 + kb + (ch & 7) * 8, wB + ch * 8);
        if (tid < 512) {
            int c2 = 1024 + tid;
            gl2lds16(fc2T + (size_t)(c2 >> 3) * 768 + kb + (c2 & 7) * 8, wB + c2 * 8);
        }
    };

    // prologue: slices 0,1 of fc1, slice 0 of fc2
    stage_fc1(0, wA0);
    stage_fc1(1, wA1);
    stage_fc2(0);

    // A3 row fragments: global→reg once, reused for all 12 hidden slices.
    short8 af[6][2];
    #pragma unroll
    for (int ks = 0; ks < 6; ++ks) {
        int c = ks * 4 + lq;
        #pragma unroll
        for (int mt = 0; mt < 2; ++mt) {
            int r = wrow * 32 + mt * 16 + lm;
            int slot = (c & ~7) | ((c ^ r) & 7);
            af[ks][mt] = *(const short8*)&A3g[(size_t)r * 192 + slot * 8];
        }
    }
    __syncthreads();   // prologue: full drain + barrier (once)

    f32x4 acc2[2][6] = {};
    for (int nb = 0; nb < 12; ++nb) {
        const short* wAc = (nb & 1) ? wA1 : wA0;
        // ---- phase A: S = gelu(A3 @ fc1slice + b1), A from regs ------------
        f32x4 acc1[2][2] = {};
        __builtin_amdgcn_s_setprio(1);
        #pragma unroll
        for (int ks = 0; ks < 6; ++ks) {
            int c = ks * 4 + lq;
            short8 bfr[2];
            #pragma unroll
            for (int nt = 0; nt < 2; ++nt) {
                int n = wcol * 32 + nt * 16 + lm;
                int slot = (c & ~7) | ((c ^ n) & 7);
                bfr[nt] = *(const short8*)&wAc[n * 192 + slot * 8];
            }
            #pragma unroll
            for (int mt = 0; mt < 2; ++mt)
                #pragma unroll
                for (int nt = 0; nt < 2; ++nt)
                    acc1[mt][nt] = __builtin_amdgcn_mfma_f32_16x16x32_bf16(af[ks][mt], bfr[nt], acc1[mt][nt], 0, 0, 0);
        }
        __builtin_amdgcn_s_setprio(0);
        #pragma unroll
        for (int nt = 0; nt < 2; ++nt) {
            int cl = wcol * 32 + nt * 16 + lm;
            float bv = b1[nb * 64 + cl];
            #pragma unroll
            for (int mt = 0; mt < 2; ++mt)
                #pragma unroll
                for (int r = 0; r < 4; ++r) {
                    int row = wrow * 32 + mt * 16 + lq * 4 + r;
                    float v = gelu_f(acc1[mt][nt][r] + bv);
                    int slot = ((cl >> 3) ^ row) & 7;
                    Sb[row * 64 + slot * 8 + (cl & 7)] = f2bf(v);
                }
        }
        // ---- pre-B sync: wB(nb)/wA(nb+1) landed (issued ≥1 phase ago) ------
        asm volatile("s_waitcnt vmcnt(0) lgkmcnt(0)" ::: "memory");
        __builtin_amdgcn_sched_barrier(0);
        __builtin_amdgcn_s_barrier();
        __builtin_amdgcn_sched_barrier(0);
        // prefetch fc1 slice nb+2 into the buffer phase A just finished with
        if (nb < 10) stage_fc1(nb + 2, (nb & 1) ? wA1 : wA0);
        // ---- phase B: acc2 += S @ fc2slice ---------------------------------
        __builtin_amdgcn_s_setprio(1);
        #pragma unroll
        for (int ks = 0; ks < 2; ++ks) {
            int c = ks * 4 + lq;                 // chunk 0..7
            short8 sf[2], wf[6];
            #pragma unroll
            for (int mt = 0; mt < 2; ++mt) {
                int r = wrow * 32 + mt * 16 + lm;
                int slot = (c ^ r) & 7;
                sf[mt] = *(const short8*)&Sb[r * 64 + slot * 8];
            }
            #pragma unroll
            for (int nt = 0; nt < 6; ++nt) {
                int o = wcol * 96 + nt * 16 + lm;
                int slot = (c ^ o) & 7;
                wf[nt] = *(const short8*)&wB[o * 64 + slot * 8];
            }
            #pragma unroll
            for (int mt = 0; mt < 2; ++mt)
                #pragma unroll
                for (int nt = 0; nt < 6; ++nt)
                    acc2[mt][nt] = __builtin_amdgcn_mfma_f32_16x16x32_bf16(sf[mt], wf[nt], acc2[mt][nt], 0, 0, 0);
        }
        __builtin_amdgcn_s_setprio(0);
        // ---- post-B sync: all waves done reading Sb/wB → safe to overwrite -
        asm volatile("s_waitcnt lgkmcnt(0)" ::: "memory");
        __builtin_amdgcn_sched_barrier(0);
        __builtin_amdgcn_s_barrier();
        __builtin_amdgcn_sched_barrier(0);
        // issue fc2 slice nb+1; phase A(nb+1) hides its latency
        if (nb < 11) stage_fc2(nb + 1);
    }
    // epilogue: direct per-lane f32x4 BCHW store. acc2[mt][nt][0..3] are rows
    // p..p+3 (p = wrow*32+mt*16+lq*4) at channel c — exactly the 4 window-cols
    // of one 16B out segment. L2 merges the 4 xq quarters of each 64B line.
    int b  = bm >> 16;
    int wh = (bm >> 10) & 63;
    int ww0 = (bm >> 4) & 63;
    int ybase = wh * 4, xbase = ww0 * 4;
    #pragma unroll
    for (int nt = 0; nt < 6; ++nt) {
        int c = wcol * 96 + nt * 16 + lm;
        float bv = b2[c];
        #pragma unroll
        for (int mt = 0; mt < 2; ++mt) {
            int p = wrow * 32 + mt * 16 + lq * 4;
            f32x4 v;
            #pragma unroll
            for (int r = 0; r < 4; ++r)
                v[r] = acc2[mt][nt][r] + bv + bf2f(xresb[(size_t)(bm + p + r) * 192 + c]);
            int wr = lq;                         // (p>>2)&3 == lq
            int xq = wrow * 2 + mt;              // p>>4
            size_t o = (((size_t)b * 192 + c) * 256 + (ybase + wr)) * 256 + xbase + xq * 4;
            *(f32x4*)&outF[o] = v;
        }
    }
}

// ---------------- launch ----------------------------------------------------
extern "C" void kernel_launch(void* const* d_in, const int* in_sizes, int n_in,
                              void* d_out, int out_size, void* d_ws, size_t ws_size,
                              hipStream_t stream) {
    const float* x      = (const float*)d_in[0];
    const float* n1g    = (const float*)d_in[1];
    const float* n1b    = (const float*)d_in[2];
    const float* w_sed  = (const float*)d_in[3];
    const float* proj_w = (const float*)d_in[4];
    const float* proj_b = (const float*)d_in[5];
    const float* n2g    = (const float*)d_in[6];
    const float* n2b    = (const float*)d_in[7];
    const float* fc1_w  = (const float*)d_in[8];
    const float* fc1_b  = (const float*)d_in[9];
    const float* fc2_w  = (const float*)d_in[10];
    const float* fc2_b  = (const float*)d_in[11];
    float* out = (float*)d_out;

    char* ws = (char*)d_ws;
    unsigned short* wfT   = (unsigned short*)(ws);                 // 18,874,368 B
    unsigned short* xw    = (unsigned short*)(ws + 18874368);      // 50,331,648 B
    unsigned short* A2    = (unsigned short*)(ws + 69206016);      // 50,331,648 B (later A3, aliased safely)
    unsigned short* xresb = (unsigned short*)(ws + 119537664);     // 50,331,648 B (xwin, then xres in-place)
    unsigned short* projT = (unsigned short*)(ws + 169869312);     // 73,728 B
    unsigned short* fc1T  = (unsigned short*)(ws + 169943040);     // 294,912 B
    unsigned short* fc2T  = (unsigned short*)(ws + 170237952);     // 294,912 B (end 170,532,864)
    unsigned short* A3    = A2;   // EPI3 writes A3 rows only after reading same A2 rows — safe

    build_wft<<<dim3(96, 96), 256, 0, stream>>>(w_sed, wfT, g_sed);
    prep_w<<<576, 256, 0, stream>>>(proj_w, fc1_w, fc2_w, projT, fc1T, fc2T);
    ln1_win<<<2048, 256, 0, stream>>>(x, n1g, n1b, xw, xresb);

    // sedenion GEMM: [8192,3072]@[3072,3072] → gelu → A2 (≡ [131072,192])
    gemm_bf16<128, 128, 0><<<dim3(64, 24), 256, 0, stream>>>(
        xw, wfT, nullptr, A2, nullptr, nullptr, nullptr, 3072, 3072);
    // proj GEMM + residual(bf16, in-place) + fused LN2 → A3 (swizzled)
    gemm_bf16<128, 192, 3><<<dim3(1024, 1), 256, 0, stream>>>(
        A2, projT, proj_b, A3, xresb, n2g, n2b, 192, 192);
    // fused FFN: fc1+gelu+fc2+residual+BCHW scatter, H1 never hits HBM
    ffn_fused<<<512, 1024, 0, stream>>>(A3, fc1T, fc2T, fc1_b, fc2_b, xresb, out);
}

// Round 3
// 797.688 us; speedup vs baseline: 1.0433x; 1.0433x over previous
//
#include <hip/hip_runtime.h>

typedef short short8 __attribute__((ext_vector_type(8)));
typedef float f32x4 __attribute__((ext_vector_type(4)));

#define DEVINL __device__ __forceinline__

// ---------------- host: sedenion sign/index table (Cayley-Dickson) ----------
struct SedTab { signed char s[256]; unsigned char j[256]; };

static void cd_mult_host(const float* a, const float* b, float* r, int n) {
    if (n == 1) { r[0] = a[0] * b[0]; return; }
    int h = n / 2;
    float cb1[8], cb2[8], t1[8], t2[8], t3[8], t4[8];
    cb1[0] = b[0]; for (int i = 1; i < h; ++i) cb1[i] = -b[i];        // conj(b1)
    cb2[0] = b[h]; for (int i = 1; i < h; ++i) cb2[i] = -b[h + i];    // conj(b2)
    cd_mult_host(a,     b,   t1, h);   // a1*b1
    cd_mult_host(cb2,   a+h, t2, h);   // conj(b2)*a2
    cd_mult_host(b+h,   a,   t3, h);   // b2*a1
    cd_mult_host(a+h,   cb1, t4, h);   // a2*conj(b1)
    for (int i = 0; i < h; ++i) { r[i] = t1[i] - t2[i]; r[h + i] = t3[i] + t4[i]; }
}

static SedTab build_sed() {
    SedTab t{};
    for (int i = 0; i < 16; ++i)
        for (int jj = 0; jj < 16; ++jj) {
            float a[16] = {0}, b[16] = {0}, r[16] = {0};
            a[i] = 1.0f; b[jj] = 1.0f;
            cd_mult_host(a, b, r, 16);
            for (int k = 0; k < 16; ++k)
                if (r[k] != 0.0f) {
                    t.s[i * 16 + k] = (r[k] > 0.f) ? 1 : -1;
                    t.j[i * 16 + k] = (unsigned char)jj;
                }
        }
    return t;
}
static const SedTab g_sed = build_sed();

// ---------------- device helpers -------------------------------------------
DEVINL unsigned short f2bf(float v) {
    union { float f; unsigned int u; } c; c.f = v;
    unsigned int r = (c.u + 0x7FFFu + ((c.u >> 16) & 1u)) >> 16;
    return (unsigned short)r;
}
DEVINL float bf2f(unsigned short u) {
    union { unsigned int i; float f; } c; c.i = ((unsigned int)u) << 16; return c.f;
}

DEVINL float gelu_f(float v) {   // tanh-approx == v*sigmoid(1.5958(v+0.044715v^3)), |err|<1.1e-3
    float u = 1.5957691216f * (v + 0.044715f * v * v * v);
    // v_rcp_f32 instead of IEEE divide sequence (~8 fewer VALU/elem; ~1ulp)
    return v * __builtin_amdgcn_rcpf(1.0f + __expf(-u));
}

DEVINL void gl2lds16(const void* g, void* l) {
    __builtin_amdgcn_global_load_lds((__attribute__((address_space(1))) const unsigned int*)g,
                                     (__attribute__((address_space(3))) unsigned int*)l, 16, 0, 0);
}

// xor-swizzle position of element k within a row (groups of 64, chunks of 8)
DEVINL int swz(int k, int row) {
    return (k & ~63) | ((((k >> 3) ^ row) & 7) << 3) | (k & 7);
}

// ---------------- wfT builder: wfT[n=(k,e)][kk=(i,dd)] = s(i,k)*w_sed[j,dd,e]
__global__ __launch_bounds__(256) void build_wft(const float* __restrict__ w_sed,
                                                 unsigned short* __restrict__ wfT,
                                                 SedTab tab) {
    __shared__ float t[32][33];
    int n0 = blockIdx.y * 32, kk0 = blockIdx.x * 32;
    int k = n0 / 192, i = kk0 / 192;            // tiles never straddle (192 = 6*32)
    int j = tab.j[i * 16 + k];
    float s = (float)tab.s[i * 16 + k];
    int e0 = n0 - k * 192, dd0 = kk0 - i * 192;
    int tx = threadIdx.x & 31, ty = threadIdx.x >> 5;
    const float* base = w_sed + ((size_t)j * 192 + dd0) * 192 + e0;
    for (int it = 0; it < 4; ++it) {
        int row = ty + it * 8;                  // row = dd index, tx = e index
        t[row][tx] = base[(size_t)row * 192 + tx];
    }
    __syncthreads();
    unsigned short* ob = wfT + (size_t)n0 * 3072 + kk0;
    for (int it = 0; it < 4; ++it) {
        int row = ty + it * 8;                  // out row = e index, tx = dd index
        ob[(size_t)row * 3072 + tx] = f2bf(s * t[tx][row]);
    }
}

// ---------------- small weights → [N][K] bf16 (fc1/fc2 pre-swizzled) --------
__global__ __launch_bounds__(256) void prep_w(const float* __restrict__ proj,
                                              const float* __restrict__ fc1,
                                              const float* __restrict__ fc2,
                                              unsigned short* __restrict__ projT,
                                              unsigned short* __restrict__ fc1T,
                                              unsigned short* __restrict__ fc2T) {
    int t = blockIdx.x * 256 + threadIdx.x;     // grid covers 147456
    if (t < 192 * 192) projT[t] = f2bf(proj[(t % 192) * 192 + t / 192]);
    if (t < 768 * 192) {
        int n = t / 192, k = t % 192;
        fc1T[n * 192 + swz(k, n)] = f2bf(fc1[(size_t)k * 768 + n]);
    }
    if (t < 192 * 768) {
        int o = t / 768, k = t % 768;
        fc2T[o * 768 + swz(k, o)] = f2bf(fc2[(size_t)k * 192 + o]);
    }
}

// ---------------- LN1 over channels + windowize; also emit raw x (bf16) -----
__global__ __launch_bounds__(256) void ln1_win(const float* __restrict__ x,
                                               const float* __restrict__ g,
                                               const float* __restrict__ bta,
                                               unsigned short* __restrict__ xw,
                                               unsigned short* __restrict__ xwin) {
    __shared__ float vals[192 * 65];
    __shared__ float ps[8][64];
    __shared__ float mrs[2][64];
    int t = threadIdx.x;
    int bid = blockIdx.x;
    int x0 = (bid & 3) << 6;
    int y  = (bid >> 2) & 255;
    int b  = bid >> 10;
    int px = t & 63, cg = t >> 6;
    const float* xp = x + ((size_t)b * 192 * 65536) + (size_t)y * 256 + x0 + px;
    float s = 0.f, s2 = 0.f;
    for (int c = cg; c < 192; c += 4) {
        float v = xp[(size_t)c * 65536];
        vals[c * 65 + px] = v;
        s += v; s2 += v * v;
    }
    ps[cg][px] = s; ps[cg + 4][px] = s2;
    __syncthreads();
    if (t < 64) {
        float S  = ps[0][t] + ps[1][t] + ps[2][t] + ps[3][t];
        float S2 = ps[4][t] + ps[5][t] + ps[6][t] + ps[7][t];
        float mean = S * (1.0f / 192.0f);
        float var  = S2 * (1.0f / 192.0f) - mean * mean;
        mrs[0][t] = mean;
        mrs[1][t] = rsqrtf(var + 1e-5f);
    }
    __syncthreads();
    int wh = y >> 2, wr = y & 3;
    for (int i = t; i < 192 * 64; i += 256) {
        int p = i / 192;
        int c = i - p * 192;
        float v = vals[c * 65 + p];
        int xx = x0 + p;
        int ww = xx >> 2, wc = xx & 3;
        int gp = ((b * 64 + wh) * 64 + ww) * 16 + wr * 4 + wc;
        size_t o = (size_t)gp * 192 + c;
        xwin[o] = f2bf(v);
        xw[o] = f2bf((v - mrs[0][p]) * mrs[1][p] * g[c] + bta[c]);
    }
}

// ---------------- bf16 MFMA GEMM, TM x TN, BK=64, XOR-swizzled LDS ----------
// A:[M,K] row-major bf16, BT:[N,K] row-major bf16 (pre-transposed B).
// EPI 0: outB bf16 = gelu(acc [+bias])                        (gemm1 sedenion)
// EPI 3: xres(bf16) += acc+bias; outB = LN2(xres) bf16, col-swizzled (gemm2)
template<int TM, int TN, int EPI>
__global__ __launch_bounds__(256, 2) void gemm_bf16(
        const unsigned short* __restrict__ A, const unsigned short* __restrict__ BT,
        const float* __restrict__ bias, unsigned short* __restrict__ outB,
        unsigned short* __restrict__ xresb,
        const float* __restrict__ g2, const float* __restrict__ b2,
        int K, int N) {
    constexpr int WN = TN / 2;
    constexpr int NT = WN / 16;
    constexpr int MT = TM / 32;
    constexpr int HR = TM / 2;
    __shared__ __align__(16) char smem[(TM * 64 + TN * 64) * 2];
    short* lsA = (short*)smem;
    short* lsB = (short*)(smem + TM * 64 * 2);
    int tid = threadIdx.x, lane = tid & 63, wid = tid >> 6;
    int wrow = wid >> 1, wcol = wid & 1;
    int lm = lane & 15, lq = lane >> 4;
    int bm = blockIdx.x * TM, bn = blockIdx.y * TN;
    const unsigned short* Ag = A + (size_t)bm * K;
    const unsigned short* Bg = BT + (size_t)bn * K;
    f32x4 acc[MT][NT] = {};
    for (int k0 = 0; k0 < K; k0 += 64) {
        #pragma unroll
        for (int it = 0; it < TM / 32; ++it) {      // stage A tile
            int p = (it * 4 + wid) * 64 + lane;
            int r = p >> 3;
            int q = (p & 7) ^ (r & 7);
            gl2lds16(Ag + (size_t)r * K + k0 + q * 8, lsA + (it * 4 + wid) * 512);
        }
        #pragma unroll
        for (int it = 0; it < TN / 32; ++it) {      // stage BT tile
            int p = (it * 4 + wid) * 64 + lane;
            int r = p >> 3;
            int q = (p & 7) ^ (r & 7);
            gl2lds16(Bg + (size_t)r * K + k0 + q * 8, lsB + (it * 4 + wid) * 512);
        }
        __syncthreads();
        #pragma unroll
        for (int s = 0; s < 2; ++s) {
            short8 af[MT], bfr[NT];
            #pragma unroll
            for (int mt = 0; mt < MT; ++mt) {
                int r = wrow * HR + mt * 16 + lm;
                int q = s * 4 + lq;
                int pos = r * 8 + (q ^ (r & 7));
                af[mt] = *(const short8*)&lsA[pos * 8];
            }
            #pragma unroll
            for (int nt = 0; nt < NT; ++nt) {
                int r = wcol * WN + nt * 16 + lm;
                int q = s * 4 + lq;
                int pos = r * 8 + (q ^ (r & 7));
                bfr[nt] = *(const short8*)&lsB[pos * 8];
            }
            #pragma unroll
            for (int mt = 0; mt < MT; ++mt)
                #pragma unroll
                for (int nt = 0; nt < NT; ++nt)
                    acc[mt][nt] = __builtin_amdgcn_mfma_f32_16x16x32_bf16(af[mt], bfr[nt], acc[mt][nt], 0, 0, 0);
        }
        __syncthreads();
    }
    // epilogue: C/D layout col=lane&15, row=lq*4+reg
    int rowB = bm + wrow * HR + lq * 4;
    int colB = bn + wcol * WN + lm;

    if constexpr (EPI == 0) {
        #pragma unroll
        for (int mt = 0; mt < MT; ++mt)
            #pragma unroll
            for (int nt = 0; nt < NT; ++nt)
                #pragma unroll
                for (int r = 0; r < 4; ++r) {
                    int gr = rowB + mt * 16 + r;
                    int gc = colB + nt * 16;
                    float v = acc[mt][nt][r];
                    if (bias) v += bias[gc];
                    outB[(size_t)gr * N + gc] = f2bf(gelu_f(v));
                }
    } else {
        // proj + residual into xres (bf16, in-place over xwin), fused LN2 →
        // outB (A3, col-swizzled for ffn_fused). TM=128, TN=192, bn=0.
        float sA[MT][4], s2A[MT][4];
        #pragma unroll
        for (int mt = 0; mt < MT; ++mt)
            #pragma unroll
            for (int r = 0; r < 4; ++r) { sA[mt][r] = 0.f; s2A[mt][r] = 0.f; }
        #pragma unroll
        for (int mt = 0; mt < MT; ++mt)
            #pragma unroll
            for (int nt = 0; nt < NT; ++nt)
                #pragma unroll
                for (int r = 0; r < 4; ++r) {
                    int gr = rowB + mt * 16 + r;
                    int gc = colB + nt * 16;
                    size_t o = (size_t)gr * 192 + gc;
                    float v = bf2f(xresb[o]) + acc[mt][nt][r] + bias[gc];
                    xresb[o] = f2bf(v);
                    acc[mt][nt][r] = v;
                    sA[mt][r] += v; s2A[mt][r] += v * v;
                }
        #pragma unroll
        for (int mt = 0; mt < MT; ++mt)
            #pragma unroll
            for (int r = 0; r < 4; ++r)
                #pragma unroll
                for (int msk = 1; msk < 16; msk <<= 1) {
                    sA[mt][r]  += __shfl_xor(sA[mt][r],  msk, 64);
                    s2A[mt][r] += __shfl_xor(s2A[mt][r], msk, 64);
                }
        float* psS   = (float*)smem;             // [128][2]
        float* psS2  = psS + 256;                // [128][2]
        float* pmean = psS2 + 256;               // [128]
        float* prsig = pmean + 128;              // [128]
        if (lm == 0) {
            #pragma unroll
            for (int mt = 0; mt < MT; ++mt)
                #pragma unroll
                for (int r = 0; r < 4; ++r) {
                    int rl = wrow * HR + mt * 16 + lq * 4 + r;
                    psS [rl * 2 + wcol] = sA[mt][r];
                    psS2[rl * 2 + wcol] = s2A[mt][r];
                }
        }
        __syncthreads();
        if (tid < TM) {
            float S  = psS[tid * 2]  + psS[tid * 2 + 1];
            float S2 = psS2[tid * 2] + psS2[tid * 2 + 1];
            float mean = S * (1.0f / 192.0f);
            float var  = S2 * (1.0f / 192.0f) - mean * mean;
            pmean[tid] = mean;
            prsig[tid] = rsqrtf(var + 1e-5f);
        }
        __syncthreads();
        float gw[NT], bw[NT];
        #pragma unroll
        for (int nt = 0; nt < NT; ++nt) {
            int gc = colB + nt * 16;
            gw[nt] = g2[gc]; bw[nt] = b2[gc];
        }
        #pragma unroll
        for (int mt = 0; mt < MT; ++mt)
            #pragma unroll
            for (int nt = 0; nt < NT; ++nt)
                #pragma unroll
                for (int r = 0; r < 4; ++r) {
                    int gr = rowB + mt * 16 + r;
                    int rl = wrow * HR + mt * 16 + lq * 4 + r;
                    int gc = colB + nt * 16;
                    float v = (acc[mt][nt][r] - pmean[rl]) * prsig[rl] * gw[nt] + bw[nt];
                    outB[(size_t)gr * 192 + swz(gc, gr)] = f2bf(v);
                }
    }
}

// ---------------- fused FFN: out = scatter(xres + gelu(A3@fc1+b1)@fc2 + b2) -
// A3: [131072][192] bf16 col-swizzled; fc1T [768][192], fc2T [192][768]
// pre-swizzled; xres bf16 plain.
// v4: v2's proven per-wave layout, replicated ×2 → 512-thread blocks, 128
// rows/block. LDS 64 KB (wA single-buffer 24K + wB 24K + Sb[128][64] 16K)
// → 2 blocks/CU = 16 waves/CU (v2: 8). fc1 staged 1-ahead after the pre-B
// barrier (wA free there; completion enforced by post-B vmcnt(0)+barrier,
// issued a full phase-B earlier). Epilogue = v2's LDS-transpose scatter in
// two 64-row passes. NOTE v3 post-mortem: no VGPR cap below ~110 (spills →
// 1.2GB HBM), no direct scatter stores (RMW amplification).
__global__ __launch_bounds__(512, 4) void ffn_fused(
        const unsigned short* __restrict__ A3, const unsigned short* __restrict__ fc1T,
        const unsigned short* __restrict__ fc2T, const float* __restrict__ b1,
        const float* __restrict__ b2, const unsigned short* __restrict__ xresb,
        float* __restrict__ outF) {
    __shared__ __align__(16) char smem[65536];
    short* wA = (short*)smem;                     // [64][192]  fc1 slice
    short* wB = (short*)(smem + 24576);           // [192][64]  fc2 slice
    short* Sb = (short*)(smem + 49152);           // [128][64]  gelu tile (wave-private rows)
    int tid = threadIdx.x, lane = tid & 63, wid = tid >> 6;   // wid 0..7
    int wrow = wid >> 1, wcol = wid & 1;                      // wrow 0..3
    int lm = lane & 15, lq = lane >> 4;
    int bm = blockIdx.x * 128;

    const unsigned short* A3g = A3 + (size_t)bm * 192;

    auto stage_fc1 = [&](int slice) {             // 1536 16B-chunks, 3/thread
        const unsigned short* f1g = fc1T + (size_t)slice * 64 * 192;  // contiguous
        #pragma unroll
        for (int it = 0; it < 3; ++it) {
            int cb = it * 512 + wid * 64;         // wave-uniform chunk base
            gl2lds16(f1g + (size_t)(cb + lane) * 8, wA + cb * 8);
        }
    };
    auto stage_fc2 = [&](int slice) {             // 1536 16B-chunks, 3/thread
        int kb = slice * 64;
        #pragma unroll
        for (int it = 0; it < 3; ++it) {
            int cb = it * 512 + wid * 64;         // wave-uniform chunk base
            int ch = cb + lane;                   // 8 chunks/row
            gl2lds16(fc2T + (size_t)(ch >> 3) * 768 + kb + (ch & 7) * 8, wB + cb * 8);
        }
    };

    // prologue: slice 0 of fc1 and fc2
    stage_fc1(0);
    stage_fc2(0);

    // A3 row fragments: global→reg once, reused for all 12 hidden slices.
    short8 af[6][2];
    #pragma unroll
    for (int ks = 0; ks < 6; ++ks) {
        int c = ks * 4 + lq;
        #pragma unroll
        for (int mt = 0; mt < 2; ++mt) {
            int r = wrow * 32 + mt * 16 + lm;
            int slot = (c & ~7) | ((c ^ r) & 7);
            af[ks][mt] = *(const short8*)&A3g[(size_t)r * 192 + slot * 8];
        }
    }
    __syncthreads();   // prologue: full drain + barrier (once)

    f32x4 acc2[2][6] = {};
    for (int nb = 0; nb < 12; ++nb) {
        // ---- phase A: S = gelu(A3 @ fc1slice + b1), A from regs ------------
        f32x4 acc1[2][2] = {};
        __builtin_amdgcn_s_setprio(1);
        #pragma unroll
        for (int ks = 0; ks < 6; ++ks) {
            int c = ks * 4 + lq;
            short8 bfr[2];
            #pragma unroll
            for (int nt = 0; nt < 2; ++nt) {
                int n = wcol * 32 + nt * 16 + lm;
                int slot = (c & ~7) | ((c ^ n) & 7);
                bfr[nt] = *(const short8*)&wA[n * 192 + slot * 8];
            }
            #pragma unroll
            for (int mt = 0; mt < 2; ++mt)
                #pragma unroll
                for (int nt = 0; nt < 2; ++nt)
                    acc1[mt][nt] = __builtin_amdgcn_mfma_f32_16x16x32_bf16(af[ks][mt], bfr[nt], acc1[mt][nt], 0, 0, 0);
        }
        __builtin_amdgcn_s_setprio(0);
        #pragma unroll
        for (int nt = 0; nt < 2; ++nt) {
            int cl = wcol * 32 + nt * 16 + lm;
            float bv = b1[nb * 64 + cl];
            #pragma unroll
            for (int mt = 0; mt < 2; ++mt)
                #pragma unroll
                for (int r = 0; r < 4; ++r) {
                    int row = wrow * 32 + mt * 16 + lq * 4 + r;
                    float v = gelu_f(acc1[mt][nt][r] + bv);
                    int slot = ((cl >> 3) ^ row) & 7;
                    Sb[row * 64 + slot * 8 + (cl & 7)] = f2bf(v);
                }
        }
        // ---- pre-B sync: Sb visible; wB(nb) landed (issued ≥1 phase ago) ---
        asm volatile("s_waitcnt vmcnt(0) lgkmcnt(0)" ::: "memory");
        __builtin_amdgcn_sched_barrier(0);
        __builtin_amdgcn_s_barrier();
        __builtin_amdgcn_sched_barrier(0);
        // refill wA with slice nb+1 (phase A done with it; phase B hides latency)
        if (nb < 11) stage_fc1(nb + 1);
        // ---- phase B: acc2 += S @ fc2slice ---------------------------------
        __builtin_amdgcn_s_setprio(1);
        #pragma unroll
        for (int ks = 0; ks < 2; ++ks) {
            int c = ks * 4 + lq;                 // chunk 0..7
            short8 sf[2], wf[6];
            #pragma unroll
            for (int mt = 0; mt < 2; ++mt) {
                int r = wrow * 32 + mt * 16 + lm;
                int slot = (c ^ r) & 7;
                sf[mt] = *(const short8*)&Sb[r * 64 + slot * 8];
            }
            #pragma unroll
            for (int nt = 0; nt < 6; ++nt) {
                int o = wcol * 96 + nt * 16 + lm;
                int slot = (c ^ o) & 7;
                wf[nt] = *(const short8*)&wB[o * 64 + slot * 8];
            }
            #pragma unroll
            for (int mt = 0; mt < 2; ++mt)
                #pragma unroll
                for (int nt = 0; nt < 6; ++nt)
                    acc2[mt][nt] = __builtin_amdgcn_mfma_f32_16x16x32_bf16(sf[mt], wf[nt], acc2[mt][nt], 0, 0, 0);
        }
        __builtin_amdgcn_s_setprio(0);
        // ---- post-B sync: Sb/wB reads done; wA(nb+1) landed ----------------
        asm volatile("s_waitcnt vmcnt(0) lgkmcnt(0)" ::: "memory");
        __builtin_amdgcn_sched_barrier(0);
        __builtin_amdgcn_s_barrier();
        __builtin_amdgcn_sched_barrier(0);
        // issue fc2 slice nb+1; phase A(nb+1) hides its latency
        if (nb < 11) stage_fc2(nb + 1);
    }
    // epilogue: + b2 + xres, LDS transpose, coalesced BCHW scatter — two
    // 64-row passes reusing T[64][201] (51.4 KB < 64 KB).
    float* T = (float*)smem;
    #pragma unroll
    for (int pass = 0; pass < 2; ++pass) {
        if ((wrow >> 1) == pass) {               // wave-uniform predicate
            #pragma unroll
            for (int nt = 0; nt < 6; ++nt) {
                int col = wcol * 96 + nt * 16 + lm;
                float bv = b2[col];
                #pragma unroll
                for (int mt = 0; mt < 2; ++mt)
                    #pragma unroll
                    for (int r = 0; r < 4; ++r) {
                        int row = wrow * 32 + mt * 16 + lq * 4 + r;   // 0..127
                        int rowT = row - pass * 64;                    // 0..63
                        float xr = bf2f(xresb[(size_t)(bm + row) * 192 + col]);
                        T[rowT * 201 + col] = acc2[mt][nt][r] + bv + xr;
                    }
            }
        }
        __syncthreads();
        int bmg = bm + pass * 64;
        int b  = bmg >> 16;
        int wh = (bmg >> 10) & 63;
        int ww0 = (bmg >> 4) & 63;
        int ybase = wh * 4, xbase = ww0 * 4;
        for (int idx = tid; idx < 3072; idx += 512) {
            int xq = idx & 3, run = idx >> 2;
            int c = run >> 2, wr = run & 3;
            int p = xq * 16 + wr * 4;
            f32x4 val;
            val[0] = T[(p + 0) * 201 + c];
            val[1] = T[(p + 1) * 201 + c];
            val[2] = T[(p + 2) * 201 + c];
            val[3] = T[(p + 3) * 201 + c];
            size_t o = (((size_t)b * 192 + c) * 256 + (ybase + wr)) * 256 + xbase + xq * 4;
            *(f32x4*)&outF[o] = val;
        }
        __syncthreads();
    }
}

// ---------------- launch ----------------------------------------------------
extern "C" void kernel_launch(void* const* d_in, const int* in_sizes, int n_in,
                              void* d_out, int out_size, void* d_ws, size_t ws_size,
                              hipStream_t stream) {
    const float* x      = (const float*)d_in[0];
    const float* n1g    = (const float*)d_in[1];
    const float* n1b    = (const float*)d_in[2];
    const float* w_sed  = (const float*)d_in[3];
    const float* proj_w = (const float*)d_in[4];
    const float* proj_b = (const float*)d_in[5];
    const float* n2g    = (const float*)d_in[6];
    const float* n2b    = (const float*)d_in[7];
    const float* fc1_w  = (const float*)d_in[8];
    const float* fc1_b  = (const float*)d_in[9];
    const float* fc2_w  = (const float*)d_in[10];
    const float* fc2_b  = (const float*)d_in[11];
    float* out = (float*)d_out;

    char* ws = (char*)d_ws;
    unsigned short* wfT   = (unsigned short*)(ws);                 // 18,874,368 B
    unsigned short* xw    = (unsigned short*)(ws + 18874368);      // 50,331,648 B
    unsigned short* A2    = (unsigned short*)(ws + 69206016);      // 50,331,648 B (later A3, aliased safely)
    unsigned short* xresb = (unsigned short*)(ws + 119537664);     // 50,331,648 B (xwin, then xres in-place)
    unsigned short* projT = (unsigned short*)(ws + 169869312);     // 73,728 B
    unsigned short* fc1T  = (unsigned short*)(ws + 169943040);     // 294,912 B
    unsigned short* fc2T  = (unsigned short*)(ws + 170237952);     // 294,912 B (end 170,532,864)
    unsigned short* A3    = A2;   // EPI3 writes A3 rows only after reading same A2 rows — safe

    build_wft<<<dim3(96, 96), 256, 0, stream>>>(w_sed, wfT, g_sed);
    prep_w<<<576, 256, 0, stream>>>(proj_w, fc1_w, fc2_w, projT, fc1T, fc2T);
    ln1_win<<<2048, 256, 0, stream>>>(x, n1g, n1b, xw, xresb);

    // sedenion GEMM: [8192,3072]@[3072,3072] → gelu → A2 (≡ [131072,192])
    gemm_bf16<128, 128, 0><<<dim3(64, 24), 256, 0, stream>>>(
        xw, wfT, nullptr, A2, nullptr, nullptr, nullptr, 3072, 3072);
    // proj GEMM + residual(bf16, in-place) + fused LN2 → A3 (swizzled)
    gemm_bf16<128, 192, 3><<<dim3(1024, 1), 256, 0, stream>>>(
        A2, projT, proj_b, A3, xresb, n2g, n2b, 192, 192);
    // fused FFN: fc1+gelu+fc2+residual+BCHW scatter, H1 never hits HBM
    ffn_fused<<<1024, 512, 0, stream>>>(A3, fc1T, fc2T, fc1_b, fc2_b, xresb, out);
}

// Round 4
// 602.939 us; speedup vs baseline: 1.3803x; 1.3230x over previous
//
#include <hip/hip_runtime.h>

typedef short short8 __attribute__((ext_vector_type(8)));
typedef float f32x4 __attribute__((ext_vector_type(4)));

#define DEVINL __device__ __forceinline__

// ---------------- host: sedenion sign/index table (Cayley-Dickson) ----------
struct SedTab { signed char s[256]; unsigned char j[256]; };

static void cd_mult_host(const float* a, const float* b, float* r, int n) {
    if (n == 1) { r[0] = a[0] * b[0]; return; }
    int h = n / 2;
    float cb1[8], cb2[8], t1[8], t2[8], t3[8], t4[8];
    cb1[0] = b[0]; for (int i = 1; i < h; ++i) cb1[i] = -b[i];        // conj(b1)
    cb2[0] = b[h]; for (int i = 1; i < h; ++i) cb2[i] = -b[h + i];    // conj(b2)
    cd_mult_host(a,     b,   t1, h);   // a1*b1
    cd_mult_host(cb2,   a+h, t2, h);   // conj(b2)*a2
    cd_mult_host(b+h,   a,   t3, h);   // b2*a1
    cd_mult_host(a+h,   cb1, t4, h);   // a2*conj(b1)
    for (int i = 0; i < h; ++i) { r[i] = t1[i] - t2[i]; r[h + i] = t3[i] + t4[i]; }
}

static SedTab build_sed() {
    SedTab t{};
    for (int i = 0; i < 16; ++i)
        for (int jj = 0; jj < 16; ++jj) {
            float a[16] = {0}, b[16] = {0}, r[16] = {0};
            a[i] = 1.0f; b[jj] = 1.0f;
            cd_mult_host(a, b, r, 16);
            for (int k = 0; k < 16; ++k)
                if (r[k] != 0.0f) {
                    t.s[i * 16 + k] = (r[k] > 0.f) ? 1 : -1;
                    t.j[i * 16 + k] = (unsigned char)jj;
                }
        }
    return t;
}
static const SedTab g_sed = build_sed();

// ---------------- device helpers -------------------------------------------
DEVINL unsigned short f2bf(float v) {
    union { float f; unsigned int u; } c; c.f = v;
    unsigned int r = (c.u + 0x7FFFu + ((c.u >> 16) & 1u)) >> 16;
    return (unsigned short)r;
}
DEVINL float bf2f(unsigned short u) {
    union { unsigned int i; float f; } c; c.i = ((unsigned int)u) << 16; return c.f;
}

DEVINL float gelu_f(float v) {   // tanh-approx == v*sigmoid(1.5958(v+0.044715v^3)), |err|<1.1e-3
    float u = 1.5957691216f * (v + 0.044715f * v * v * v);
    // v_rcp_f32 instead of IEEE divide sequence (~8 fewer VALU/elem; ~1ulp)
    return v * __builtin_amdgcn_rcpf(1.0f + __expf(-u));
}

DEVINL void gl2lds16(const void* g, void* l) {
    __builtin_amdgcn_global_load_lds((__attribute__((address_space(1))) const unsigned int*)g,
                                     (__attribute__((address_space(3))) unsigned int*)l, 16, 0, 0);
}

// xor-swizzle position of element k within a row (groups of 64, chunks of 8)
DEVINL int swz(int k, int row) {
    return (k & ~63) | ((((k >> 3) ^ row) & 7) << 3) | (k & 7);
}

// ---------------- wfT builder: wfT[n=(k,e)][kk=(i,dd)] = s(i,k)*w_sed[j,dd,e]
__global__ __launch_bounds__(256) void build_wft(const float* __restrict__ w_sed,
                                                 unsigned short* __restrict__ wfT,
                                                 SedTab tab) {
    __shared__ float t[32][33];
    int n0 = blockIdx.y * 32, kk0 = blockIdx.x * 32;
    int k = n0 / 192, i = kk0 / 192;            // tiles never straddle (192 = 6*32)
    int j = tab.j[i * 16 + k];
    float s = (float)tab.s[i * 16 + k];
    int e0 = n0 - k * 192, dd0 = kk0 - i * 192;
    int tx = threadIdx.x & 31, ty = threadIdx.x >> 5;
    const float* base = w_sed + ((size_t)j * 192 + dd0) * 192 + e0;
    for (int it = 0; it < 4; ++it) {
        int row = ty + it * 8;                  // row = dd index, tx = e index
        t[row][tx] = base[(size_t)row * 192 + tx];
    }
    __syncthreads();
    unsigned short* ob = wfT + (size_t)n0 * 3072 + kk0;
    for (int it = 0; it < 4; ++it) {
        int row = ty + it * 8;                  // out row = e index, tx = dd index
        ob[(size_t)row * 3072 + tx] = f2bf(s * t[tx][row]);
    }
}

// ---------------- small weights → [N][K] bf16 (fc1/fc2 pre-swizzled) --------
__global__ __launch_bounds__(256) void prep_w(const float* __restrict__ proj,
                                              const float* __restrict__ fc1,
                                              const float* __restrict__ fc2,
                                              unsigned short* __restrict__ projT,
                                              unsigned short* __restrict__ fc1T,
                                              unsigned short* __restrict__ fc2T) {
    int t = blockIdx.x * 256 + threadIdx.x;     // grid covers 147456
    if (t < 192 * 192) projT[t] = f2bf(proj[(t % 192) * 192 + t / 192]);
    if (t < 768 * 192) {
        int n = t / 192, k = t % 192;
        fc1T[n * 192 + swz(k, n)] = f2bf(fc1[(size_t)k * 768 + n]);
    }
    if (t < 192 * 768) {
        int o = t / 768, k = t % 768;
        fc2T[o * 768 + swz(k, o)] = f2bf(fc2[(size_t)k * 192 + o]);
    }
}

// ---------------- LN1 over channels + windowize; also emit raw x (bf16) -----
__global__ __launch_bounds__(256) void ln1_win(const float* __restrict__ x,
                                               const float* __restrict__ g,
                                               const float* __restrict__ bta,
                                               unsigned short* __restrict__ xw,
                                               unsigned short* __restrict__ xwin) {
    __shared__ float vals[192 * 65];
    __shared__ float ps[8][64];
    __shared__ float mrs[2][64];
    int t = threadIdx.x;
    int bid = blockIdx.x;
    int x0 = (bid & 3) << 6;
    int y  = (bid >> 2) & 255;
    int b  = bid >> 10;
    int px = t & 63, cg = t >> 6;
    const float* xp = x + ((size_t)b * 192 * 65536) + (size_t)y * 256 + x0 + px;
    float s = 0.f, s2 = 0.f;
    for (int c = cg; c < 192; c += 4) {
        float v = xp[(size_t)c * 65536];
        vals[c * 65 + px] = v;
        s += v; s2 += v * v;
    }
    ps[cg][px] = s; ps[cg + 4][px] = s2;
    __syncthreads();
    if (t < 64) {
        float S  = ps[0][t] + ps[1][t] + ps[2][t] + ps[3][t];
        float S2 = ps[4][t] + ps[5][t] + ps[6][t] + ps[7][t];
        float mean = S * (1.0f / 192.0f);
        float var  = S2 * (1.0f / 192.0f) - mean * mean;
        mrs[0][t] = mean;
        mrs[1][t] = rsqrtf(var + 1e-5f);
    }
    __syncthreads();
    int wh = y >> 2, wr = y & 3;
    for (int i = t; i < 192 * 64; i += 256) {
        int p = i / 192;
        int c = i - p * 192;
        float v = vals[c * 65 + p];
        int xx = x0 + p;
        int ww = xx >> 2, wc = xx & 3;
        int gp = ((b * 64 + wh) * 64 + ww) * 16 + wr * 4 + wc;
        size_t o = (size_t)gp * 192 + c;
        xwin[o] = f2bf(v);
        xw[o] = f2bf((v - mrs[0][p]) * mrs[1][p] * g[c] + bta[c]);
    }
}

// ---------------- bf16 MFMA GEMM, TM x TN, BK=64, XOR-swizzled LDS ----------
// A:[M,K] row-major bf16, BT:[N,K] row-major bf16 (pre-transposed B).
// EPI 0: outB bf16 = gelu(acc [+bias])                        (gemm1 sedenion)
// EPI 3: xres(bf16) += acc+bias; outB = LN2(xres) bf16, col-swizzled (gemm2)
template<int TM, int TN, int EPI>
__global__ __launch_bounds__(256, 2) void gemm_bf16(
        const unsigned short* __restrict__ A, const unsigned short* __restrict__ BT,
        const float* __restrict__ bias, unsigned short* __restrict__ outB,
        unsigned short* __restrict__ xresb,
        const float* __restrict__ g2, const float* __restrict__ b2,
        int K, int N) {
    constexpr int WN = TN / 2;
    constexpr int NT = WN / 16;
    constexpr int MT = TM / 32;
    constexpr int HR = TM / 2;
    __shared__ __align__(16) char smem[(TM * 64 + TN * 64) * 2];
    short* lsA = (short*)smem;
    short* lsB = (short*)(smem + TM * 64 * 2);
    int tid = threadIdx.x, lane = tid & 63, wid = tid >> 6;
    int wrow = wid >> 1, wcol = wid & 1;
    int lm = lane & 15, lq = lane >> 4;
    int bm = blockIdx.x * TM, bn = blockIdx.y * TN;
    const unsigned short* Ag = A + (size_t)bm * K;
    const unsigned short* Bg = BT + (size_t)bn * K;
    f32x4 acc[MT][NT] = {};
    for (int k0 = 0; k0 < K; k0 += 64) {
        #pragma unroll
        for (int it = 0; it < TM / 32; ++it) {      // stage A tile
            int p = (it * 4 + wid) * 64 + lane;
            int r = p >> 3;
            int q = (p & 7) ^ (r & 7);
            gl2lds16(Ag + (size_t)r * K + k0 + q * 8, lsA + (it * 4 + wid) * 512);
        }
        #pragma unroll
        for (int it = 0; it < TN / 32; ++it) {      // stage BT tile
            int p = (it * 4 + wid) * 64 + lane;
            int r = p >> 3;
            int q = (p & 7) ^ (r & 7);
            gl2lds16(Bg + (size_t)r * K + k0 + q * 8, lsB + (it * 4 + wid) * 512);
        }
        __syncthreads();
        #pragma unroll
        for (int s = 0; s < 2; ++s) {
            short8 af[MT], bfr[NT];
            #pragma unroll
            for (int mt = 0; mt < MT; ++mt) {
                int r = wrow * HR + mt * 16 + lm;
                int q = s * 4 + lq;
                int pos = r * 8 + (q ^ (r & 7));
                af[mt] = *(const short8*)&lsA[pos * 8];
            }
            #pragma unroll
            for (int nt = 0; nt < NT; ++nt) {
                int r = wcol * WN + nt * 16 + lm;
                int q = s * 4 + lq;
                int pos = r * 8 + (q ^ (r & 7));
                bfr[nt] = *(const short8*)&lsB[pos * 8];
            }
            #pragma unroll
            for (int mt = 0; mt < MT; ++mt)
                #pragma unroll
                for (int nt = 0; nt < NT; ++nt)
                    acc[mt][nt] = __builtin_amdgcn_mfma_f32_16x16x32_bf16(af[mt], bfr[nt], acc[mt][nt], 0, 0, 0);
        }
        __syncthreads();
    }
    // epilogue: C/D layout col=lane&15, row=lq*4+reg
    int rowB = bm + wrow * HR + lq * 4;
    int colB = bn + wcol * WN + lm;

    if constexpr (EPI == 0) {
        #pragma unroll
        for (int mt = 0; mt < MT; ++mt)
            #pragma unroll
            for (int nt = 0; nt < NT; ++nt)
                #pragma unroll
                for (int r = 0; r < 4; ++r) {
                    int gr = rowB + mt * 16 + r;
                    int gc = colB + nt * 16;
                    float v = acc[mt][nt][r];
                    if (bias) v += bias[gc];
                    outB[(size_t)gr * N + gc] = f2bf(gelu_f(v));
                }
    } else {
        // proj + residual into xres (bf16, in-place over xwin), fused LN2 →
        // outB (A3, col-swizzled for ffn_fused). TM=128, TN=192, bn=0.
        float sA[MT][4], s2A[MT][4];
        #pragma unroll
        for (int mt = 0; mt < MT; ++mt)
            #pragma unroll
            for (int r = 0; r < 4; ++r) { sA[mt][r] = 0.f; s2A[mt][r] = 0.f; }
        #pragma unroll
        for (int mt = 0; mt < MT; ++mt)
            #pragma unroll
            for (int nt = 0; nt < NT; ++nt)
                #pragma unroll
                for (int r = 0; r < 4; ++r) {
                    int gr = rowB + mt * 16 + r;
                    int gc = colB + nt * 16;
                    size_t o = (size_t)gr * 192 + gc;
                    float v = bf2f(xresb[o]) + acc[mt][nt][r] + bias[gc];
                    xresb[o] = f2bf(v);
                    acc[mt][nt][r] = v;
                    sA[mt][r] += v; s2A[mt][r] += v * v;
                }
        #pragma unroll
        for (int mt = 0; mt < MT; ++mt)
            #pragma unroll
            for (int r = 0; r < 4; ++r)
                #pragma unroll
                for (int msk = 1; msk < 16; msk <<= 1) {
                    sA[mt][r]  += __shfl_xor(sA[mt][r],  msk, 64);
                    s2A[mt][r] += __shfl_xor(s2A[mt][r], msk, 64);
                }
        float* psS   = (float*)smem;             // [128][2]
        float* psS2  = psS + 256;                // [128][2]
        float* pmean = psS2 + 256;               // [128]
        float* prsig = pmean + 128;              // [128]
        if (lm == 0) {
            #pragma unroll
            for (int mt = 0; mt < MT; ++mt)
                #pragma unroll
                for (int r = 0; r < 4; ++r) {
                    int rl = wrow * HR + mt * 16 + lq * 4 + r;
                    psS [rl * 2 + wcol] = sA[mt][r];
                    psS2[rl * 2 + wcol] = s2A[mt][r];
                }
        }
        __syncthreads();
        if (tid < TM) {
            float S  = psS[tid * 2]  + psS[tid * 2 + 1];
            float S2 = psS2[tid * 2] + psS2[tid * 2 + 1];
            float mean = S * (1.0f / 192.0f);
            float var  = S2 * (1.0f / 192.0f) - mean * mean;
            pmean[tid] = mean;
            prsig[tid] = rsqrtf(var + 1e-5f);
        }
        __syncthreads();
        float gw[NT], bw[NT];
        #pragma unroll
        for (int nt = 0; nt < NT; ++nt) {
            int gc = colB + nt * 16;
            gw[nt] = g2[gc]; bw[nt] = b2[gc];
        }
        #pragma unroll
        for (int mt = 0; mt < MT; ++mt)
            #pragma unroll
            for (int nt = 0; nt < NT; ++nt)
                #pragma unroll
                for (int r = 0; r < 4; ++r) {
                    int gr = rowB + mt * 16 + r;
                    int rl = wrow * HR + mt * 16 + lq * 4 + r;
                    int gc = colB + nt * 16;
                    float v = (acc[mt][nt][r] - pmean[rl]) * prsig[rl] * gw[nt] + bw[nt];
                    outB[(size_t)gr * 192 + swz(gc, gr)] = f2bf(v);
                }
    }
}

// ---------------- fused FFN: out = scatter(xres + gelu(A3@fc1+b1)@fc2 + b2) -
// A3: [131072][192] bf16 col-swizzled; fc1T [768][192], fc2T [192][768]
// pre-swizzled; xres bf16 plain.
// v5: identical to v4 except __launch_bounds__(512, 2). v3/v4 post-mortem:
// second arg 4 made the compiler allocate only 64 VGPRs (it behaves as if
// demanding 8 waves/SIMD residency) → ~115-VGPR working set spilled to
// scratch → +450MB HBM traffic. With arg 2 the cap is 256; natural
// allocation ~110 ≤ 128 still gives 4 waves/SIMD (LDS 64KB → 2 blocks/CU).
__global__ __launch_bounds__(512, 2) void ffn_fused(
        const unsigned short* __restrict__ A3, const unsigned short* __restrict__ fc1T,
        const unsigned short* __restrict__ fc2T, const float* __restrict__ b1,
        const float* __restrict__ b2, const unsigned short* __restrict__ xresb,
        float* __restrict__ outF) {
    __shared__ __align__(16) char smem[65536];
    short* wA = (short*)smem;                     // [64][192]  fc1 slice
    short* wB = (short*)(smem + 24576);           // [192][64]  fc2 slice
    short* Sb = (short*)(smem + 49152);           // [128][64]  gelu tile (wave-private rows)
    int tid = threadIdx.x, lane = tid & 63, wid = tid >> 6;   // wid 0..7
    int wrow = wid >> 1, wcol = wid & 1;                      // wrow 0..3
    int lm = lane & 15, lq = lane >> 4;
    int bm = blockIdx.x * 128;

    const unsigned short* A3g = A3 + (size_t)bm * 192;

    auto stage_fc1 = [&](int slice) {             // 1536 16B-chunks, 3/thread
        const unsigned short* f1g = fc1T + (size_t)slice * 64 * 192;  // contiguous
        #pragma unroll
        for (int it = 0; it < 3; ++it) {
            int cb = it * 512 + wid * 64;         // wave-uniform chunk base
            gl2lds16(f1g + (size_t)(cb + lane) * 8, wA + cb * 8);
        }
    };
    auto stage_fc2 = [&](int slice) {             // 1536 16B-chunks, 3/thread
        int kb = slice * 64;
        #pragma unroll
        for (int it = 0; it < 3; ++it) {
            int cb = it * 512 + wid * 64;         // wave-uniform chunk base
            int ch = cb + lane;                   // 8 chunks/row
            gl2lds16(fc2T + (size_t)(ch >> 3) * 768 + kb + (ch & 7) * 8, wB + cb * 8);
        }
    };

    // prologue: slice 0 of fc1 and fc2
    stage_fc1(0);
    stage_fc2(0);

    // A3 row fragments: global→reg once, reused for all 12 hidden slices.
    short8 af[6][2];
    #pragma unroll
    for (int ks = 0; ks < 6; ++ks) {
        int c = ks * 4 + lq;
        #pragma unroll
        for (int mt = 0; mt < 2; ++mt) {
            int r = wrow * 32 + mt * 16 + lm;
            int slot = (c & ~7) | ((c ^ r) & 7);
            af[ks][mt] = *(const short8*)&A3g[(size_t)r * 192 + slot * 8];
        }
    }
    __syncthreads();   // prologue: full drain + barrier (once)

    f32x4 acc2[2][6] = {};
    for (int nb = 0; nb < 12; ++nb) {
        // ---- phase A: S = gelu(A3 @ fc1slice + b1), A from regs ------------
        f32x4 acc1[2][2] = {};
        __builtin_amdgcn_s_setprio(1);
        #pragma unroll
        for (int ks = 0; ks < 6; ++ks) {
            int c = ks * 4 + lq;
            short8 bfr[2];
            #pragma unroll
            for (int nt = 0; nt < 2; ++nt) {
                int n = wcol * 32 + nt * 16 + lm;
                int slot = (c & ~7) | ((c ^ n) & 7);
                bfr[nt] = *(const short8*)&wA[n * 192 + slot * 8];
            }
            #pragma unroll
            for (int mt = 0; mt < 2; ++mt)
                #pragma unroll
                for (int nt = 0; nt < 2; ++nt)
                    acc1[mt][nt] = __builtin_amdgcn_mfma_f32_16x16x32_bf16(af[ks][mt], bfr[nt], acc1[mt][nt], 0, 0, 0);
        }
        __builtin_amdgcn_s_setprio(0);
        #pragma unroll
        for (int nt = 0; nt < 2; ++nt) {
            int cl = wcol * 32 + nt * 16 + lm;
            float bv = b1[nb * 64 + cl];
            #pragma unroll
            for (int mt = 0; mt < 2; ++mt)
                #pragma unroll
                for (int r = 0; r < 4; ++r) {
                    int row = wrow * 32 + mt * 16 + lq * 4 + r;
                    float v = gelu_f(acc1[mt][nt][r] + bv);
                    int slot = ((cl >> 3) ^ row) & 7;
                    Sb[row * 64 + slot * 8 + (cl & 7)] = f2bf(v);
                }
        }
        // ---- pre-B sync: Sb visible; wB(nb) landed (issued ≥1 phase ago) ---
        asm volatile("s_waitcnt vmcnt(0) lgkmcnt(0)" ::: "memory");
        __builtin_amdgcn_sched_barrier(0);
        __builtin_amdgcn_s_barrier();
        __builtin_amdgcn_sched_barrier(0);
        // refill wA with slice nb+1 (phase A done with it; phase B hides latency)
        if (nb < 11) stage_fc1(nb + 1);
        // ---- phase B: acc2 += S @ fc2slice ---------------------------------
        __builtin_amdgcn_s_setprio(1);
        #pragma unroll
        for (int ks = 0; ks < 2; ++ks) {
            int c = ks * 4 + lq;                 // chunk 0..7
            short8 sf[2], wf[6];
            #pragma unroll
            for (int mt = 0; mt < 2; ++mt) {
                int r = wrow * 32 + mt * 16 + lm;
                int slot = (c ^ r) & 7;
                sf[mt] = *(const short8*)&Sb[r * 64 + slot * 8];
            }
            #pragma unroll
            for (int nt = 0; nt < 6; ++nt) {
                int o = wcol * 96 + nt * 16 + lm;
                int slot = (c ^ o) & 7;
                wf[nt] = *(const short8*)&wB[o * 64 + slot * 8];
            }
            #pragma unroll
            for (int mt = 0; mt < 2; ++mt)
                #pragma unroll
                for (int nt = 0; nt < 6; ++nt)
                    acc2[mt][nt] = __builtin_amdgcn_mfma_f32_16x16x32_bf16(sf[mt], wf[nt], acc2[mt][nt], 0, 0, 0);
        }
        __builtin_amdgcn_s_setprio(0);
        // ---- post-B sync: Sb/wB reads done; wA(nb+1) landed ----------------
        asm volatile("s_waitcnt vmcnt(0) lgkmcnt(0)" ::: "memory");
        __builtin_amdgcn_sched_barrier(0);
        __builtin_amdgcn_s_barrier();
        __builtin_amdgcn_sched_barrier(0);
        // issue fc2 slice nb+1; phase A(nb+1) hides its latency
        if (nb < 11) stage_fc2(nb + 1);
    }
    // epilogue: + b2 + xres, LDS transpose, coalesced BCHW scatter — two
    // 64-row passes reusing T[64][201] (51.4 KB < 64 KB).
    float* T = (float*)smem;
    #pragma unroll
    for (int pass = 0; pass < 2; ++pass) {
        if ((wrow >> 1) == pass) {               // wave-uniform predicate
            #pragma unroll
            for (int nt = 0; nt < 6; ++nt) {
                int col = wcol * 96 + nt * 16 + lm;
                float bv = b2[col];
                #pragma unroll
                for (int mt = 0; mt < 2; ++mt)
                    #pragma unroll
                    for (int r = 0; r < 4; ++r) {
                        int row = wrow * 32 + mt * 16 + lq * 4 + r;   // 0..127
                        int rowT = row - pass * 64;                    // 0..63
                        float xr = bf2f(xresb[(size_t)(bm + row) * 192 + col]);
                        T[rowT * 201 + col] = acc2[mt][nt][r] + bv + xr;
                    }
            }
        }
        __syncthreads();
        int bmg = bm + pass * 64;
        int b  = bmg >> 16;
        int wh = (bmg >> 10) & 63;
        int ww0 = (bmg >> 4) & 63;
        int ybase = wh * 4, xbase = ww0 * 4;
        for (int idx = tid; idx < 3072; idx += 512) {
            int xq = idx & 3, run = idx >> 2;
            int c = run >> 2, wr = run & 3;
            int p = xq * 16 + wr * 4;
            f32x4 val;
            val[0] = T[(p + 0) * 201 + c];
            val[1] = T[(p + 1) * 201 + c];
            val[2] = T[(p + 2) * 201 + c];
            val[3] = T[(p + 3) * 201 + c];
            size_t o = (((size_t)b * 192 + c) * 256 + (ybase + wr)) * 256 + xbase + xq * 4;
            *(f32x4*)&outF[o] = val;
        }
        __syncthreads();
    }
}

// ---------------- launch ----------------------------------------------------
extern "C" void kernel_launch(void* const* d_in, const int* in_sizes, int n_in,
                              void* d_out, int out_size, void* d_ws, size_t ws_size,
                              hipStream_t stream) {
    const float* x      = (const float*)d_in[0];
    const float* n1g    = (const float*)d_in[1];
    const float* n1b    = (const float*)d_in[2];
    const float* w_sed  = (const float*)d_in[3];
    const float* proj_w = (const float*)d_in[4];
    const float* proj_b = (const float*)d_in[5];
    const float* n2g    = (const float*)d_in[6];
    const float* n2b    = (const float*)d_in[7];
    const float* fc1_w  = (const float*)d_in[8];
    const float* fc1_b  = (const float*)d_in[9];
    const float* fc2_w  = (const float*)d_in[10];
    const float* fc2_b  = (const float*)d_in[11];
    float* out = (float*)d_out;

    char* ws = (char*)d_ws;
    unsigned short* wfT   = (unsigned short*)(ws);                 // 18,874,368 B
    unsigned short* xw    = (unsigned short*)(ws + 18874368);      // 50,331,648 B
    unsigned short* A2    = (unsigned short*)(ws + 69206016);      // 50,331,648 B (later A3, aliased safely)
    unsigned short* xresb = (unsigned short*)(ws + 119537664);     // 50,331,648 B (xwin, then xres in-place)
    unsigned short* projT = (unsigned short*)(ws + 169869312);     // 73,728 B
    unsigned short* fc1T  = (unsigned short*)(ws + 169943040);     // 294,912 B
    unsigned short* fc2T  = (unsigned short*)(ws + 170237952);     // 294,912 B (end 170,532,864)
    unsigned short* A3    = A2;   // EPI3 writes A3 rows only after reading same A2 rows — safe

    build_wft<<<dim3(96, 96), 256, 0, stream>>>(w_sed, wfT, g_sed);
    prep_w<<<576, 256, 0, stream>>>(proj_w, fc1_w, fc2_w, projT, fc1T, fc2T);
    ln1_win<<<2048, 256, 0, stream>>>(x, n1g, n1b, xw, xresb);

    // sedenion GEMM: [8192,3072]@[3072,3072] → gelu → A2 (≡ [131072,192])
    gemm_bf16<128, 128, 0><<<dim3(64, 24), 256, 0, stream>>>(
        xw, wfT, nullptr, A2, nullptr, nullptr, nullptr, 3072, 3072);
    // proj GEMM + residual(bf16, in-place) + fused LN2 → A3 (swizzled)
    gemm_bf16<128, 192, 3><<<dim3(1024, 1), 256, 0, stream>>>(
        A2, projT, proj_b, A3, xresb, n2g, n2b, 192, 192);
    // fused FFN: fc1+gelu+fc2+residual+BCHW scatter, H1 never hits HBM
    ffn_fused<<<1024, 512, 0, stream>>>(A3, fc1T, fc2T, fc1_b, fc2_b, xresb, out);
}

// Round 5
// 576.176 us; speedup vs baseline: 1.4444x; 1.0464x over previous
//
#include <hip/hip_runtime.h>

typedef short short8 __attribute__((ext_vector_type(8)));
typedef float f32x4 __attribute__((ext_vector_type(4)));

#define DEVINL __device__ __forceinline__

// ---------------- host: sedenion sign/index table (Cayley-Dickson) ----------
struct SedTab { signed char s[256]; unsigned char j[256]; };

static void cd_mult_host(const float* a, const float* b, float* r, int n) {
    if (n == 1) { r[0] = a[0] * b[0]; return; }
    int h = n / 2;
    float cb1[8], cb2[8], t1[8], t2[8], t3[8], t4[8];
    cb1[0] = b[0]; for (int i = 1; i < h; ++i) cb1[i] = -b[i];        // conj(b1)
    cb2[0] = b[h]; for (int i = 1; i < h; ++i) cb2[i] = -b[h + i];    // conj(b2)
    cd_mult_host(a,     b,   t1, h);   // a1*b1
    cd_mult_host(cb2,   a+h, t2, h);   // conj(b2)*a2
    cd_mult_host(b+h,   a,   t3, h);   // b2*a1
    cd_mult_host(a+h,   cb1, t4, h);   // a2*conj(b1)
    for (int i = 0; i < h; ++i) { r[i] = t1[i] - t2[i]; r[h + i] = t3[i] + t4[i]; }
}

static SedTab build_sed() {
    SedTab t{};
    for (int i = 0; i < 16; ++i)
        for (int jj = 0; jj < 16; ++jj) {
            float a[16] = {0}, b[16] = {0}, r[16] = {0};
            a[i] = 1.0f; b[jj] = 1.0f;
            cd_mult_host(a, b, r, 16);
            for (int k = 0; k < 16; ++k)
                if (r[k] != 0.0f) {
                    t.s[i * 16 + k] = (r[k] > 0.f) ? 1 : -1;
                    t.j[i * 16 + k] = (unsigned char)jj;
                }
        }
    return t;
}
static const SedTab g_sed = build_sed();

// ---------------- device helpers -------------------------------------------
DEVINL unsigned short f2bf(float v) {
    union { float f; unsigned int u; } c; c.f = v;
    unsigned int r = (c.u + 0x7FFFu + ((c.u >> 16) & 1u)) >> 16;
    return (unsigned short)r;
}
DEVINL float bf2f(unsigned short u) {
    union { unsigned int i; float f; } c; c.i = ((unsigned int)u) << 16; return c.f;
}

DEVINL float gelu_f(float v) {   // tanh-approx == v*sigmoid(1.5958(v+0.044715v^3)), |err|<1.1e-3
    float u = 1.5957691216f * (v + 0.044715f * v * v * v);
    // v_rcp_f32 instead of IEEE divide sequence (~8 fewer VALU/elem; ~1ulp)
    return v * __builtin_amdgcn_rcpf(1.0f + __expf(-u));
}

DEVINL void gl2lds16(const void* g, void* l) {
    __builtin_amdgcn_global_load_lds((__attribute__((address_space(1))) const unsigned int*)g,
                                     (__attribute__((address_space(3))) unsigned int*)l, 16, 0, 0);
}

// xor-swizzle position of element k within a row (groups of 64, chunks of 8)
DEVINL int swz(int k, int row) {
    return (k & ~63) | ((((k >> 3) ^ row) & 7) << 3) | (k & 7);
}

// ---------------- wfT builder: wfT[n=(k,e)][kk=(i,dd)] = s(i,k)*w_sed[j,dd,e]
__global__ __launch_bounds__(256) void build_wft(const float* __restrict__ w_sed,
                                                 unsigned short* __restrict__ wfT,
                                                 SedTab tab) {
    __shared__ float t[32][33];
    int n0 = blockIdx.y * 32, kk0 = blockIdx.x * 32;
    int k = n0 / 192, i = kk0 / 192;            // tiles never straddle (192 = 6*32)
    int j = tab.j[i * 16 + k];
    float s = (float)tab.s[i * 16 + k];
    int e0 = n0 - k * 192, dd0 = kk0 - i * 192;
    int tx = threadIdx.x & 31, ty = threadIdx.x >> 5;
    const float* base = w_sed + ((size_t)j * 192 + dd0) * 192 + e0;
    for (int it = 0; it < 4; ++it) {
        int row = ty + it * 8;                  // row = dd index, tx = e index
        t[row][tx] = base[(size_t)row * 192 + tx];
    }
    __syncthreads();
    unsigned short* ob = wfT + (size_t)n0 * 3072 + kk0;
    for (int it = 0; it < 4; ++it) {
        int row = ty + it * 8;                  // out row = e index, tx = dd index
        ob[(size_t)row * 3072 + tx] = f2bf(s * t[tx][row]);
    }
}

// ---------------- small weights → [N][K] bf16 (fc1/fc2 pre-swizzled) --------
__global__ __launch_bounds__(256) void prep_w(const float* __restrict__ proj,
                                              const float* __restrict__ fc1,
                                              const float* __restrict__ fc2,
                                              unsigned short* __restrict__ projT,
                                              unsigned short* __restrict__ fc1T,
                                              unsigned short* __restrict__ fc2T) {
    int t = blockIdx.x * 256 + threadIdx.x;     // grid covers 147456
    if (t < 192 * 192) projT[t] = f2bf(proj[(t % 192) * 192 + t / 192]);
    if (t < 768 * 192) {
        int n = t / 192, k = t % 192;
        fc1T[n * 192 + swz(k, n)] = f2bf(fc1[(size_t)k * 768 + n]);
    }
    if (t < 192 * 768) {
        int o = t / 768, k = t % 768;
        fc2T[o * 768 + swz(k, o)] = f2bf(fc2[(size_t)k * 192 + o]);
    }
}

// ---------------- LN1 over channels + windowize; also emit raw x (bf16) -----
__global__ __launch_bounds__(256) void ln1_win(const float* __restrict__ x,
                                               const float* __restrict__ g,
                                               const float* __restrict__ bta,
                                               unsigned short* __restrict__ xw,
                                               unsigned short* __restrict__ xwin) {
    __shared__ float vals[192 * 65];
    __shared__ float ps[8][64];
    __shared__ float mrs[2][64];
    int t = threadIdx.x;
    int bid = blockIdx.x;
    int x0 = (bid & 3) << 6;
    int y  = (bid >> 2) & 255;
    int b  = bid >> 10;
    int px = t & 63, cg = t >> 6;
    const float* xp = x + ((size_t)b * 192 * 65536) + (size_t)y * 256 + x0 + px;
    float s = 0.f, s2 = 0.f;
    for (int c = cg; c < 192; c += 4) {
        float v = xp[(size_t)c * 65536];
        vals[c * 65 + px] = v;
        s += v; s2 += v * v;
    }
    ps[cg][px] = s; ps[cg + 4][px] = s2;
    __syncthreads();
    if (t < 64) {
        float S  = ps[0][t] + ps[1][t] + ps[2][t] + ps[3][t];
        float S2 = ps[4][t] + ps[5][t] + ps[6][t] + ps[7][t];
        float mean = S * (1.0f / 192.0f);
        float var  = S2 * (1.0f / 192.0f) - mean * mean;
        mrs[0][t] = mean;
        mrs[1][t] = rsqrtf(var + 1e-5f);
    }
    __syncthreads();
    int wh = y >> 2, wr = y & 3;
    for (int i = t; i < 192 * 64; i += 256) {
        int p = i / 192;
        int c = i - p * 192;
        float v = vals[c * 65 + p];
        int xx = x0 + p;
        int ww = xx >> 2, wc = xx & 3;
        int gp = ((b * 64 + wh) * 64 + ww) * 16 + wr * 4 + wc;
        size_t o = (size_t)gp * 192 + c;
        xwin[o] = f2bf(v);
        xw[o] = f2bf((v - mrs[0][p]) * mrs[1][p] * g[c] + bta[c]);
    }
}

// ---------------- fused sedenion GEMM + gelu + proj + residual + LN2 --------
// v6: replaces gemm1 (EPI0) AND gemm2 (EPI3). TM=128, TN=192, grid (64,16).
// Block (bx,by) computes A2 rows gp=(bx*128+r)*16+by for ALL 192 channels
// (TN=192 spans the full channel dim), so proj (192x192) + residual + LN2
// complete in-block: gelu tile -> LDS (bf16, chunk-swizzled), mini-GEMM vs
// projT (K=192, 3 staged slices, +144 MFMA/wave vs 2304 main), then the
// debugged EPI3 epilogue. A2 never touches HBM; gemm2's ~130us disappears.
__global__ __launch_bounds__(256, 2) void gemm_fused(
        const unsigned short* __restrict__ A,      // xw [8192][3072]
        const unsigned short* __restrict__ BT,     // wfT [3072][3072]
        const unsigned short* __restrict__ projTw, // [192][192] (N,K) bf16
        const float* __restrict__ pbias,
        unsigned short* __restrict__ outB,         // A3 [131072][192] swizzled
        unsigned short* __restrict__ xresb,        // xres bf16, RMW in-place
        const float* __restrict__ g2, const float* __restrict__ b2) {
    constexpr int K = 3072;
    __shared__ __align__(16) char smem[73728];
    short* lsA = (short*)smem;                    // main loop: [0, 16K)
    short* lsB = (short*)(smem + 16384);          // main loop: [16K, 40K)
    short* A2t = (short*)smem;                    // epilogue: [0, 48K) gelu tile
    short* lsP = (short*)(smem + 49152);          // epilogue: [48K, 72K) projT slice
    int tid = threadIdx.x, lane = tid & 63, wid = tid >> 6;
    int wrow = wid >> 1, wcol = wid & 1;
    int lm = lane & 15, lq = lane >> 4;
    int bm = blockIdx.x * 128;                    // window-row base (0..8191)
    int by = blockIdx.y;                          // pixel-slot k (0..15)
    const unsigned short* Ag = A + (size_t)bm * K;
    const unsigned short* Bg = BT + (size_t)by * 192 * K;
    f32x4 acc[4][6] = {};
    for (int k0 = 0; k0 < K; k0 += 64) {
        #pragma unroll
        for (int it = 0; it < 4; ++it) {            // stage A tile [128][64]
            int p = (it * 4 + wid) * 64 + lane;
            int r = p >> 3;
            int q = (p & 7) ^ (r & 7);
            gl2lds16(Ag + (size_t)r * K + k0 + q * 8, lsA + (it * 4 + wid) * 512);
        }
        #pragma unroll
        for (int it = 0; it < 6; ++it) {            // stage BT tile [192][64]
            int p = (it * 4 + wid) * 64 + lane;
            int r = p >> 3;
            int q = (p & 7) ^ (r & 7);
            gl2lds16(Bg + (size_t)r * K + k0 + q * 8, lsB + (it * 4 + wid) * 512);
        }
        __syncthreads();
        #pragma unroll
        for (int s = 0; s < 2; ++s) {
            short8 af[4], bfr[6];
            #pragma unroll
            for (int mt = 0; mt < 4; ++mt) {
                int r = wrow * 64 + mt * 16 + lm;
                int q = s * 4 + lq;
                int pos = r * 8 + (q ^ (r & 7));
                af[mt] = *(const short8*)&lsA[pos * 8];
            }
            #pragma unroll
            for (int nt = 0; nt < 6; ++nt) {
                int r = wcol * 96 + nt * 16 + lm;
                int q = s * 4 + lq;
                int pos = r * 8 + (q ^ (r & 7));
                bfr[nt] = *(const short8*)&lsB[pos * 8];
            }
            #pragma unroll
            for (int mt = 0; mt < 4; ++mt)
                #pragma unroll
                for (int nt = 0; nt < 6; ++nt)
                    acc[mt][nt] = __builtin_amdgcn_mfma_f32_16x16x32_bf16(af[mt], bfr[nt], acc[mt][nt], 0, 0, 0);
        }
        __syncthreads();
    }
    // ---- epi 1: gelu(acc) -> A2t bf16 (chunk-swizzled), then zero acc ------
    // C/D layout: col = lane&15, row = lq*4 + reg.
    #pragma unroll
    for (int mt = 0; mt < 4; ++mt)
        #pragma unroll
        for (int nt = 0; nt < 6; ++nt)
            #pragma unroll
            for (int r = 0; r < 4; ++r) {
                int row = wrow * 64 + mt * 16 + lq * 4 + r;
                int c = wcol * 96 + nt * 16 + lm;
                A2t[row * 192 + swz(c, row)] = f2bf(gelu_f(acc[mt][nt][r]));
            }
    #pragma unroll
    for (int mt = 0; mt < 4; ++mt)
        #pragma unroll
        for (int nt = 0; nt < 6; ++nt)
            acc[mt][nt] = f32x4{0.f, 0.f, 0.f, 0.f};
    __syncthreads();
    // ---- epi 2: acc = A2t @ projT (K=192, 3 slices of 64) ------------------
    for (int k0 = 0; k0 < 192; k0 += 64) {
        #pragma unroll
        for (int it = 0; it < 6; ++it) {            // stage projT slice [192][64]
            int p = (it * 4 + wid) * 64 + lane;
            int r = p >> 3;
            int q = (p & 7) ^ (r & 7);
            gl2lds16(projTw + (size_t)r * 192 + k0 + q * 8, lsP + (it * 4 + wid) * 512);
        }
        __syncthreads();
        #pragma unroll
        for (int s = 0; s < 2; ++s) {
            short8 af[4], bfr[6];
            #pragma unroll
            for (int mt = 0; mt < 4; ++mt) {
                int r = wrow * 64 + mt * 16 + lm;
                int cg = (k0 >> 3) + s * 4 + lq;    // global chunk 0..23
                int slot = (cg & ~7) | ((cg ^ r) & 7);
                af[mt] = *(const short8*)&A2t[r * 192 + slot * 8];
            }
            #pragma unroll
            for (int nt = 0; nt < 6; ++nt) {
                int r = wcol * 96 + nt * 16 + lm;
                int q = s * 4 + lq;
                int pos = r * 8 + (q ^ (r & 7));
                bfr[nt] = *(const short8*)&lsP[pos * 8];
            }
            #pragma unroll
            for (int mt = 0; mt < 4; ++mt)
                #pragma unroll
                for (int nt = 0; nt < 6; ++nt)
                    acc[mt][nt] = __builtin_amdgcn_mfma_f32_16x16x32_bf16(af[mt], bfr[nt], acc[mt][nt], 0, 0, 0);
        }
        __syncthreads();
    }
    // ---- epi 3: xres RMW + LN2 + swizzled A3 write (gp = (bm+rl)*16 + by) --
    float sA[4][4], s2A[4][4];
    #pragma unroll
    for (int mt = 0; mt < 4; ++mt)
        #pragma unroll
        for (int r = 0; r < 4; ++r) { sA[mt][r] = 0.f; s2A[mt][r] = 0.f; }
    #pragma unroll
    for (int mt = 0; mt < 4; ++mt)
        #pragma unroll
        for (int nt = 0; nt < 6; ++nt)
            #pragma unroll
            for (int r = 0; r < 4; ++r) {
                int rl = wrow * 64 + mt * 16 + lq * 4 + r;
                int gc = wcol * 96 + nt * 16 + lm;
                size_t gp = (size_t)(bm + rl) * 16 + by;
                size_t o = gp * 192 + gc;
                float v = bf2f(xresb[o]) + acc[mt][nt][r] + pbias[gc];
                xresb[o] = f2bf(v);
                acc[mt][nt][r] = v;
                sA[mt][r] += v; s2A[mt][r] += v * v;
            }
    #pragma unroll
    for (int mt = 0; mt < 4; ++mt)
        #pragma unroll
        for (int r = 0; r < 4; ++r)
            #pragma unroll
            for (int msk = 1; msk < 16; msk <<= 1) {
                sA[mt][r]  += __shfl_xor(sA[mt][r],  msk, 64);
                s2A[mt][r] += __shfl_xor(s2A[mt][r], msk, 64);
            }
    float* psS   = (float*)smem;             // [128][2]  (overlays dead A2t)
    float* psS2  = psS + 256;                // [128][2]
    float* pmean = psS2 + 256;               // [128]
    float* prsig = pmean + 128;              // [128]
    if (lm == 0) {
        #pragma unroll
        for (int mt = 0; mt < 4; ++mt)
            #pragma unroll
            for (int r = 0; r < 4; ++r) {
                int rl = wrow * 64 + mt * 16 + lq * 4 + r;
                psS [rl * 2 + wcol] = sA[mt][r];
                psS2[rl * 2 + wcol] = s2A[mt][r];
            }
    }
    __syncthreads();
    if (tid < 128) {
        float S  = psS[tid * 2]  + psS[tid * 2 + 1];
        float S2 = psS2[tid * 2] + psS2[tid * 2 + 1];
        float mean = S * (1.0f / 192.0f);
        float var  = S2 * (1.0f / 192.0f) - mean * mean;
        pmean[tid] = mean;
        prsig[tid] = rsqrtf(var + 1e-5f);
    }
    __syncthreads();
    float gw[6], bw[6];
    #pragma unroll
    for (int nt = 0; nt < 6; ++nt) {
        int gc = wcol * 96 + nt * 16 + lm;
        gw[nt] = g2[gc]; bw[nt] = b2[gc];
    }
    #pragma unroll
    for (int mt = 0; mt < 4; ++mt)
        #pragma unroll
        for (int nt = 0; nt < 6; ++nt)
            #pragma unroll
            for (int r = 0; r < 4; ++r) {
                int rl = wrow * 64 + mt * 16 + lq * 4 + r;
                int gc = wcol * 96 + nt * 16 + lm;
                int gp = (bm + rl) * 16 + by;
                float v = (acc[mt][nt][r] - pmean[rl]) * prsig[rl] * gw[nt] + bw[nt];
                outB[(size_t)gp * 192 + swz(gc, gp)] = f2bf(v);
            }
}

// ---------------- fused FFN: out = scatter(xres + gelu(A3@fc1+b1)@fc2 + b2) -
// A3: [131072][192] bf16 col-swizzled; fc1T [768][192], fc2T [192][768]
// pre-swizzled; xres bf16 plain. (v5 structure, unchanged.)
__global__ __launch_bounds__(512, 2) void ffn_fused(
        const unsigned short* __restrict__ A3, const unsigned short* __restrict__ fc1T,
        const unsigned short* __restrict__ fc2T, const float* __restrict__ b1,
        const float* __restrict__ b2, const unsigned short* __restrict__ xresb,
        float* __restrict__ outF) {
    __shared__ __align__(16) char smem[65536];
    short* wA = (short*)smem;                     // [64][192]  fc1 slice
    short* wB = (short*)(smem + 24576);           // [192][64]  fc2 slice
    short* Sb = (short*)(smem + 49152);           // [128][64]  gelu tile (wave-private rows)
    int tid = threadIdx.x, lane = tid & 63, wid = tid >> 6;   // wid 0..7
    int wrow = wid >> 1, wcol = wid & 1;                      // wrow 0..3
    int lm = lane & 15, lq = lane >> 4;
    int bm = blockIdx.x * 128;

    const unsigned short* A3g = A3 + (size_t)bm * 192;

    auto stage_fc1 = [&](int slice) {             // 1536 16B-chunks, 3/thread
        const unsigned short* f1g = fc1T + (size_t)slice * 64 * 192;  // contiguous
        #pragma unroll
        for (int it = 0; it < 3; ++it) {
            int cb = it * 512 + wid * 64;         // wave-uniform chunk base
            gl2lds16(f1g + (size_t)(cb + lane) * 8, wA + cb * 8);
        }
    };
    auto stage_fc2 = [&](int slice) {             // 1536 16B-chunks, 3/thread
        int kb = slice * 64;
        #pragma unroll
        for (int it = 0; it < 3; ++it) {
            int cb = it * 512 + wid * 64;         // wave-uniform chunk base
            int ch = cb + lane;                   // 8 chunks/row
            gl2lds16(fc2T + (size_t)(ch >> 3) * 768 + kb + (ch & 7) * 8, wB + cb * 8);
        }
    };

    // prologue: slice 0 of fc1 and fc2
    stage_fc1(0);
    stage_fc2(0);

    // A3 row fragments: global→reg once, reused for all 12 hidden slices.
    short8 af[6][2];
    #pragma unroll
    for (int ks = 0; ks < 6; ++ks) {
        int c = ks * 4 + lq;
        #pragma unroll
        for (int mt = 0; mt < 2; ++mt) {
            int r = wrow * 32 + mt * 16 + lm;
            int slot = (c & ~7) | ((c ^ r) & 7);
            af[ks][mt] = *(const short8*)&A3g[(size_t)r * 192 + slot * 8];
        }
    }
    __syncthreads();   // prologue: full drain + barrier (once)

    f32x4 acc2[2][6] = {};
    for (int nb = 0; nb < 12; ++nb) {
        // ---- phase A: S = gelu(A3 @ fc1slice + b1), A from regs ------------
        f32x4 acc1[2][2] = {};
        __builtin_amdgcn_s_setprio(1);
        #pragma unroll
        for (int ks = 0; ks < 6; ++ks) {
            int c = ks * 4 + lq;
            short8 bfr[2];
            #pragma unroll
            for (int nt = 0; nt < 2; ++nt) {
                int n = wcol * 32 + nt * 16 + lm;
                int slot = (c & ~7) | ((c ^ n) & 7);
                bfr[nt] = *(const short8*)&wA[n * 192 + slot * 8];
            }
            #pragma unroll
            for (int mt = 0; mt < 2; ++mt)
                #pragma unroll
                for (int nt = 0; nt < 2; ++nt)
                    acc1[mt][nt] = __builtin_amdgcn_mfma_f32_16x16x32_bf16(af[ks][mt], bfr[nt], acc1[mt][nt], 0, 0, 0);
        }
        __builtin_amdgcn_s_setprio(0);
        #pragma unroll
        for (int nt = 0; nt < 2; ++nt) {
            int cl = wcol * 32 + nt * 16 + lm;
            float bv = b1[nb * 64 + cl];
            #pragma unroll
            for (int mt = 0; mt < 2; ++mt)
                #pragma unroll
                for (int r = 0; r < 4; ++r) {
                    int row = wrow * 32 + mt * 16 + lq * 4 + r;
                    float v = gelu_f(acc1[mt][nt][r] + bv);
                    int slot = ((cl >> 3) ^ row) & 7;
                    Sb[row * 64 + slot * 8 + (cl & 7)] = f2bf(v);
                }
        }
        // ---- pre-B sync: Sb visible; wB(nb) landed (issued ≥1 phase ago) ---
        asm volatile("s_waitcnt vmcnt(0) lgkmcnt(0)" ::: "memory");
        __builtin_amdgcn_sched_barrier(0);
        __builtin_amdgcn_s_barrier();
        __builtin_amdgcn_sched_barrier(0);
        // refill wA with slice nb+1 (phase A done with it; phase B hides latency)
        if (nb < 11) stage_fc1(nb + 1);
        // ---- phase B: acc2 += S @ fc2slice ---------------------------------
        __builtin_amdgcn_s_setprio(1);
        #pragma unroll
        for (int ks = 0; ks < 2; ++ks) {
            int c = ks * 4 + lq;                 // chunk 0..7
            short8 sf[2], wf[6];
            #pragma unroll
            for (int mt = 0; mt < 2; ++mt) {
                int r = wrow * 32 + mt * 16 + lm;
                int slot = (c ^ r) & 7;
                sf[mt] = *(const short8*)&Sb[r * 64 + slot * 8];
            }
            #pragma unroll
            for (int nt = 0; nt < 6; ++nt) {
                int o = wcol * 96 + nt * 16 + lm;
                int slot = (c ^ o) & 7;
                wf[nt] = *(const short8*)&wB[o * 64 + slot * 8];
            }
            #pragma unroll
            for (int mt = 0; mt < 2; ++mt)
                #pragma unroll
                for (int nt = 0; nt < 6; ++nt)
                    acc2[mt][nt] = __builtin_amdgcn_mfma_f32_16x16x32_bf16(sf[mt], wf[nt], acc2[mt][nt], 0, 0, 0);
        }
        __builtin_amdgcn_s_setprio(0);
        // ---- post-B sync: Sb/wB reads done; wA(nb+1) landed ----------------
        asm volatile("s_waitcnt vmcnt(0) lgkmcnt(0)" ::: "memory");
        __builtin_amdgcn_sched_barrier(0);
        __builtin_amdgcn_s_barrier();
        __builtin_amdgcn_sched_barrier(0);
        // issue fc2 slice nb+1; phase A(nb+1) hides its latency
        if (nb < 11) stage_fc2(nb + 1);
    }
    // epilogue: + b2 + xres, LDS transpose, coalesced BCHW scatter — two
    // 64-row passes reusing T[64][201] (51.4 KB < 64 KB).
    float* T = (float*)smem;
    #pragma unroll
    for (int pass = 0; pass < 2; ++pass) {
        if ((wrow >> 1) == pass) {               // wave-uniform predicate
            #pragma unroll
            for (int nt = 0; nt < 6; ++nt) {
                int col = wcol * 96 + nt * 16 + lm;
                float bv = b2[col];
                #pragma unroll
                for (int mt = 0; mt < 2; ++mt)
                    #pragma unroll
                    for (int r = 0; r < 4; ++r) {
                        int row = wrow * 32 + mt * 16 + lq * 4 + r;   // 0..127
                        int rowT = row - pass * 64;                    // 0..63
                        float xr = bf2f(xresb[(size_t)(bm + row) * 192 + col]);
                        T[rowT * 201 + col] = acc2[mt][nt][r] + bv + xr;
                    }
            }
        }
        __syncthreads();
        int bmg = bm + pass * 64;
        int b  = bmg >> 16;
        int wh = (bmg >> 10) & 63;
        int ww0 = (bmg >> 4) & 63;
        int ybase = wh * 4, xbase = ww0 * 4;
        for (int idx = tid; idx < 3072; idx += 512) {
            int xq = idx & 3, run = idx >> 2;
            int c = run >> 2, wr = run & 3;
            int p = xq * 16 + wr * 4;
            f32x4 val;
            val[0] = T[(p + 0) * 201 + c];
            val[1] = T[(p + 1) * 201 + c];
            val[2] = T[(p + 2) * 201 + c];
            val[3] = T[(p + 3) * 201 + c];
            size_t o = (((size_t)b * 192 + c) * 256 + (ybase + wr)) * 256 + xbase + xq * 4;
            *(f32x4*)&outF[o] = val;
        }
        __syncthreads();
    }
}

// ---------------- launch ----------------------------------------------------
extern "C" void kernel_launch(void* const* d_in, const int* in_sizes, int n_in,
                              void* d_out, int out_size, void* d_ws, size_t ws_size,
                              hipStream_t stream) {
    const float* x      = (const float*)d_in[0];
    const float* n1g    = (const float*)d_in[1];
    const float* n1b    = (const float*)d_in[2];
    const float* w_sed  = (const float*)d_in[3];
    const float* proj_w = (const float*)d_in[4];
    const float* proj_b = (const float*)d_in[5];
    const float* n2g    = (const float*)d_in[6];
    const float* n2b    = (const float*)d_in[7];
    const float* fc1_w  = (const float*)d_in[8];
    const float* fc1_b  = (const float*)d_in[9];
    const float* fc2_w  = (const float*)d_in[10];
    const float* fc2_b  = (const float*)d_in[11];
    float* out = (float*)d_out;

    char* ws = (char*)d_ws;
    unsigned short* wfT   = (unsigned short*)(ws);                 // 18,874,368 B
    unsigned short* xw    = (unsigned short*)(ws + 18874368);      // 50,331,648 B
    unsigned short* A3    = (unsigned short*)(ws + 69206016);      // 50,331,648 B (A2 slot, now A3 only)
    unsigned short* xresb = (unsigned short*)(ws + 119537664);     // 50,331,648 B (xwin, then xres in-place)
    unsigned short* projT = (unsigned short*)(ws + 169869312);     // 73,728 B
    unsigned short* fc1T  = (unsigned short*)(ws + 169943040);     // 294,912 B
    unsigned short* fc2T  = (unsigned short*)(ws + 170237952);     // 294,912 B (end 170,532,864)

    build_wft<<<dim3(96, 96), 256, 0, stream>>>(w_sed, wfT, g_sed);
    prep_w<<<576, 256, 0, stream>>>(proj_w, fc1_w, fc2_w, projT, fc1T, fc2T);
    ln1_win<<<2048, 256, 0, stream>>>(x, n1g, n1b, xw, xresb);

    // sedenion GEMM + gelu + proj + residual + LN2, all fused:
    // [8192,3072]@[3072,3072] -> gelu -> @projT -> xres RMW -> LN2 -> A3
    gemm_fused<<<dim3(64, 16), 256, 0, stream>>>(
        xw, wfT, projT, proj_b, A3, xresb, n2g, n2b);
    // fused FFN: fc1+gelu+fc2+residual+BCHW scatter, H1 never hits HBM
    ffn_fused<<<1024, 512, 0, stream>>>(A3, fc1T, fc2T, fc1_b, fc2_b, xresb, out);
}